// Round 1
// baseline (922.541 us; speedup 1.0000x reference)
//
#include <hip/hip_runtime.h>
#include <hip/hip_bf16.h>

#define DEV_INLINE __device__ __forceinline__

DEV_INLINE float lrelu(float v) { return fmaxf(v, 0.2f * v); }

// ---------------------------------------------------------------------------
// CSR build kernels
// ---------------------------------------------------------------------------
__global__ void k_count(const int* __restrict__ ei, int* __restrict__ counts, int E) {
    int e = blockIdx.x * blockDim.x + threadIdx.x;
    if (e < E) atomicAdd(&counts[ei[E + e]], 1);
}

__global__ __launch_bounds__(1024) void k_scan1(const int* __restrict__ counts,
                                                int* __restrict__ rowptr,
                                                int* __restrict__ partials, int N) {
    __shared__ int sd[1024];
    int li = threadIdx.x;
    int i  = blockIdx.x * 1024 + li;
    int v  = (i < N) ? counts[i] : 0;
    sd[li] = v;
    __syncthreads();
    for (int off = 1; off < 1024; off <<= 1) {
        int t = (li >= off) ? sd[li - off] : 0;
        __syncthreads();
        sd[li] += t;
        __syncthreads();
    }
    int inc = sd[li];
    if (i < N) rowptr[i + 1] = inc;
    if (li == 1023) partials[blockIdx.x] = inc;
}

__global__ void k_scan2(int* __restrict__ partials, int NB) {
    if (threadIdx.x == 0 && blockIdx.x == 0) {
        int run = 0;
        for (int b = 0; b < NB; ++b) { int t = partials[b]; partials[b] = run; run += t; }
    }
}

__global__ void k_scan3(int* __restrict__ rowptr, const int* __restrict__ partials,
                        int* __restrict__ nxt, int N) {
    int i = blockIdx.x * blockDim.x + threadIdx.x;
    if (i > N) return;
    int v;
    if (i == 0) { v = 0; rowptr[0] = 0; }
    else        { v = rowptr[i] + partials[(i - 1) >> 10]; rowptr[i] = v; }
    if (i < N) nxt[i] = v;
}

__global__ void k_scatter(const int* __restrict__ ei, int* __restrict__ nxt,
                          int* __restrict__ col, int E) {
    int e = blockIdx.x * blockDim.x + threadIdx.x;
    if (e < E) {
        int d   = ei[E + e];
        int pos = atomicAdd(&nxt[d], 1);
        col[pos] = ei[e];
    }
}

// ---------------------------------------------------------------------------
// Temporal encoder: t = mean_t( relu(x_t @ W1 + b1) ) @ W2 + b2
// one wave per node; lane = output channel
// ---------------------------------------------------------------------------
__global__ __launch_bounds__(256) void k_temporal(const float* __restrict__ td,
                                                  const float* __restrict__ tW1,
                                                  const float* __restrict__ tb1,
                                                  const float* __restrict__ tW2,
                                                  const float* __restrict__ tb2,
                                                  float* __restrict__ t_enc, int N) {
    __shared__ float W2s[64 * 64];
    __shared__ float sm[4][64];
    int tid = threadIdx.x;
    for (int i = tid; i < 64 * 64; i += 256) W2s[i] = tW2[i];
    int wave = tid >> 6, lane = tid & 63;
    int n0 = blockIdx.x * 4 + wave;
    int n  = __builtin_amdgcn_readfirstlane(n0 < N ? n0 : N - 1);

    float w1c[10];
#pragma unroll
    for (int i = 0; i < 10; ++i) w1c[i] = tW1[i * 64 + lane];
    float b1 = tb1[lane];

    const float* xp = td + (size_t)n * 500;
    float acc = 0.f;
#pragma unroll 5
    for (int t = 0; t < 50; ++t) {
        float u = b1;
#pragma unroll
        for (int i = 0; i < 10; ++i) u = fmaf(xp[t * 10 + i], w1c[i], u);
        acc += fmaxf(u, 0.f);
    }
    acc *= (1.f / 50.f);

    __syncthreads();          // W2s staged
    sm[wave][lane] = acc;
    __syncthreads();

    float o = tb2[lane];
#pragma unroll 8
    for (int i = 0; i < 64; ++i) o = fmaf(sm[wave][i], W2s[i * 64 + lane], o);
    if (n0 < N) t_enc[(size_t)n * 64 + lane] = o;
}

// ---------------------------------------------------------------------------
// GATConv1 projection + attention scores. h1[n,128], a1s[n,4], a1d[n,4]
// ---------------------------------------------------------------------------
__global__ __launch_bounds__(256) void k_g1a(const float* __restrict__ x,
                                             const float* __restrict__ gW1,
                                             const float* __restrict__ as_w,
                                             const float* __restrict__ ad_w,
                                             float* __restrict__ h1,
                                             float* __restrict__ a1s,
                                             float* __restrict__ a1d, int N) {
    int tid = threadIdx.x, lane = tid & 63;
    int n0 = blockIdx.x * 4 + (tid >> 6);
    int n  = __builtin_amdgcn_readfirstlane(n0 < N ? n0 : N - 1);

    float wa[10], wb[10];
#pragma unroll
    for (int i = 0; i < 10; ++i) { wa[i] = gW1[i * 128 + lane]; wb[i] = gW1[i * 128 + 64 + lane]; }
    const float* xp = x + (size_t)n * 10;
    float ha = 0.f, hb = 0.f;
#pragma unroll
    for (int i = 0; i < 10; ++i) { float xv = xp[i]; ha = fmaf(xv, wa[i], ha); hb = fmaf(xv, wb[i], hb); }

    int c = lane & 31;
    int headA = lane >> 5;            // 0 or 1; second channel -> heads 2,3
    float ps_a = ha * as_w[headA * 32 + c];
    float ps_b = hb * as_w[(headA + 2) * 32 + c];
    float pd_a = ha * ad_w[headA * 32 + c];
    float pd_b = hb * ad_w[(headA + 2) * 32 + c];
#pragma unroll
    for (int m = 1; m < 32; m <<= 1) {
        ps_a += __shfl_xor(ps_a, m); ps_b += __shfl_xor(ps_b, m);
        pd_a += __shfl_xor(pd_a, m); pd_b += __shfl_xor(pd_b, m);
    }
    if (n0 < N) {
        h1[(size_t)n * 128 + lane]      = ha;
        h1[(size_t)n * 128 + 64 + lane] = hb;
        if (c == 0) {
            a1s[n * 4 + headA]     = ps_a;
            a1s[n * 4 + 2 + headA] = ps_b;
            a1d[n * 4 + headA]     = pd_a;
            a1d[n * 4 + 2 + headA] = pd_b;
        }
    }
}

// ---------------------------------------------------------------------------
// GATConv1 aggregation + bias + ELU. wave per dst node, lanes = channels
// ---------------------------------------------------------------------------
__global__ __launch_bounds__(256) void k_g1b(const int* __restrict__ rowptr,
                                             const int* __restrict__ col,
                                             const float* __restrict__ h1,
                                             const float* __restrict__ a1s,
                                             const float* __restrict__ a1d,
                                             const float* __restrict__ gb1,
                                             float* __restrict__ out1, int N) {
    int tid = threadIdx.x, lane = tid & 63;
    int n0 = blockIdx.x * 4 + (tid >> 6);
    int n  = __builtin_amdgcn_readfirstlane(n0 < N ? n0 : N - 1);

    int start = rowptr[n], end = rowptr[n + 1];
    const float4* a1s4 = reinterpret_cast<const float4*>(a1s);
    float4 adv = reinterpret_cast<const float4*>(a1d)[n];
    float4 asv = a1s4[n];
    float es0 = lrelu(asv.x + adv.x), es1 = lrelu(asv.y + adv.y);
    float es2 = lrelu(asv.z + adv.z), es3 = lrelu(asv.w + adv.w);
    float m0 = es0, m1 = es1, m2 = es2, m3 = es3;

    for (int e = start + lane; e < end; e += 64) {
        int s = col[e];
        float4 q = a1s4[s];
        m0 = fmaxf(m0, lrelu(q.x + adv.x));
        m1 = fmaxf(m1, lrelu(q.y + adv.y));
        m2 = fmaxf(m2, lrelu(q.z + adv.z));
        m3 = fmaxf(m3, lrelu(q.w + adv.w));
    }
#pragma unroll
    for (int msk = 1; msk < 64; msk <<= 1) {
        m0 = fmaxf(m0, __shfl_xor(m0, msk));
        m1 = fmaxf(m1, __shfl_xor(m1, msk));
        m2 = fmaxf(m2, __shfl_xor(m2, msk));
        m3 = fmaxf(m3, __shfl_xor(m3, msk));
    }

    // self loop
    float w0 = __expf(es0 - m0), w1 = __expf(es1 - m1);
    float w2 = __expf(es2 - m2), w3 = __expf(es3 - m3);
    float den0 = w0, den1 = w1, den2 = w2, den3 = w3;
    const float* hn = h1 + (size_t)n * 128;
    float acc1 = ((lane < 32) ? w0 : w1) * hn[lane];
    float acc2 = ((lane < 32) ? w2 : w3) * hn[64 + lane];

    for (int e = start; e < end; ++e) {
        int s = col[e];                       // loop-uniform -> scalar loads
        float4 q = a1s4[s];
        float e0 = __expf(lrelu(q.x + adv.x) - m0);
        float e1 = __expf(lrelu(q.y + adv.y) - m1);
        float e2 = __expf(lrelu(q.z + adv.z) - m2);
        float e3 = __expf(lrelu(q.w + adv.w) - m3);
        den0 += e0; den1 += e1; den2 += e2; den3 += e3;
        const float* hs = h1 + (size_t)s * 128;
        acc1 = fmaf((lane < 32) ? e0 : e1, hs[lane], acc1);
        acc2 = fmaf((lane < 32) ? e2 : e3, hs[64 + lane], acc2);
    }

    float v1 = acc1 / ((lane < 32) ? den0 : den1) + gb1[lane];
    float v2 = acc2 / ((lane < 32) ? den2 : den3) + gb1[64 + lane];
    v1 = (v1 > 0.f) ? v1 : (__expf(v1) - 1.f);   // ELU
    v2 = (v2 > 0.f) ? v2 : (__expf(v2) - 1.f);
    if (n0 < N) {
        out1[(size_t)n * 128 + lane]      = v1;
        out1[(size_t)n * 128 + 64 + lane] = v2;
    }
}

// ---------------------------------------------------------------------------
// GATConv2 projection (128->64) + attention scores
// ---------------------------------------------------------------------------
__global__ __launch_bounds__(256) void k_g2a(const float* __restrict__ out1,
                                             const float* __restrict__ gW2,
                                             const float* __restrict__ a2sw,
                                             const float* __restrict__ a2dw,
                                             float* __restrict__ h2,
                                             float* __restrict__ a2s,
                                             float* __restrict__ a2d, int N) {
    __shared__ float Ws[128 * 64];
    int tid = threadIdx.x, lane = tid & 63;
    for (int i = tid; i < 128 * 64; i += 256) Ws[i] = gW2[i];
    __syncthreads();
    int n0 = blockIdx.x * 4 + (tid >> 6);
    int n  = __builtin_amdgcn_readfirstlane(n0 < N ? n0 : N - 1);

    const float* xr = out1 + (size_t)n * 128;
    float acc = 0.f;
#pragma unroll
    for (int i0 = 0; i0 < 128; i0 += 8) {
        float xv[8];
#pragma unroll
        for (int k = 0; k < 8; ++k) xv[k] = xr[i0 + k];
#pragma unroll
        for (int k = 0; k < 8; ++k) acc = fmaf(xv[k], Ws[(i0 + k) * 64 + lane], acc);
    }
    float ps = acc * a2sw[lane], pd = acc * a2dw[lane];
#pragma unroll
    for (int msk = 1; msk < 64; msk <<= 1) { ps += __shfl_xor(ps, msk); pd += __shfl_xor(pd, msk); }
    if (n0 < N) {
        h2[(size_t)n * 64 + lane] = acc;
        if (lane == 0) { a2s[n] = ps; a2d[n] = pd; }
    }
}

// ---------------------------------------------------------------------------
// GATConv2 aggregation + bias. wave per dst node
// ---------------------------------------------------------------------------
__global__ __launch_bounds__(256) void k_g2b(const int* __restrict__ rowptr,
                                             const int* __restrict__ col,
                                             const float* __restrict__ h2,
                                             const float* __restrict__ a2s,
                                             const float* __restrict__ a2d,
                                             const float* __restrict__ gb2,
                                             float* __restrict__ g, int N) {
    int tid = threadIdx.x, lane = tid & 63;
    int n0 = blockIdx.x * 4 + (tid >> 6);
    int n  = __builtin_amdgcn_readfirstlane(n0 < N ? n0 : N - 1);

    int start = rowptr[n], end = rowptr[n + 1];
    float ad  = a2d[n];
    float es  = lrelu(a2s[n] + ad);
    float m   = es;
    for (int e = start + lane; e < end; e += 64)
        m = fmaxf(m, lrelu(a2s[col[e]] + ad));
#pragma unroll
    for (int msk = 1; msk < 64; msk <<= 1) m = fmaxf(m, __shfl_xor(m, msk));

    float w   = __expf(es - m);
    float den = w;
    float acc = w * h2[(size_t)n * 64 + lane];
    for (int e = start; e < end; ++e) {
        int s = col[e];
        float wv = __expf(lrelu(a2s[s] + ad) - m);
        den += wv;
        acc = fmaf(wv, h2[(size_t)s * 64 + lane], acc);
    }
    if (n0 < N) g[(size_t)n * 64 + lane] = acc / den + gb2[lane];
}

// ---------------------------------------------------------------------------
// Classifier: sigmoid(relu([t,g] @ cW1 + cb1) @ cW2 + cb2)
// ---------------------------------------------------------------------------
__global__ __launch_bounds__(256) void k_cls(const float* __restrict__ t_enc,
                                             const float* __restrict__ g,
                                             const float* __restrict__ cW1,
                                             const float* __restrict__ cb1,
                                             const float* __restrict__ cW2,
                                             const float* __restrict__ cb2,
                                             float* __restrict__ out, int N) {
    __shared__ float Ws[128 * 64];
    int tid = threadIdx.x, lane = tid & 63;
    for (int i = tid; i < 128 * 64; i += 256) Ws[i] = cW1[i];
    __syncthreads();
    int n0 = blockIdx.x * 4 + (tid >> 6);
    int n  = __builtin_amdgcn_readfirstlane(n0 < N ? n0 : N - 1);

    const float* tp = t_enc + (size_t)n * 64;
    const float* gp = g + (size_t)n * 64;
    float acc = cb1[lane];
#pragma unroll
    for (int i0 = 0; i0 < 64; i0 += 8) {
        float xv[8];
#pragma unroll
        for (int k = 0; k < 8; ++k) xv[k] = tp[i0 + k];
#pragma unroll
        for (int k = 0; k < 8; ++k) acc = fmaf(xv[k], Ws[(i0 + k) * 64 + lane], acc);
    }
#pragma unroll
    for (int i0 = 0; i0 < 64; i0 += 8) {
        float xv[8];
#pragma unroll
        for (int k = 0; k < 8; ++k) xv[k] = gp[i0 + k];
#pragma unroll
        for (int k = 0; k < 8; ++k) acc = fmaf(xv[k], Ws[(64 + i0 + k) * 64 + lane], acc);
    }
    acc = fmaxf(acc, 0.f);
    float p = acc * cW2[lane];
#pragma unroll
    for (int msk = 1; msk < 64; msk <<= 1) p += __shfl_xor(p, msk);
    if (n0 < N && lane == 0) out[n] = 1.f / (1.f + __expf(-(p + cb2[0])));
}

// ---------------------------------------------------------------------------
extern "C" void kernel_launch(void* const* d_in, const int* in_sizes, int n_in,
                              void* d_out, int out_size, void* d_ws, size_t ws_size,
                              hipStream_t stream) {
    const float* td   = (const float*)d_in[0];
    const float* x    = (const float*)d_in[1];
    const int*   ei   = (const int*)d_in[2];
    const float* tW1  = (const float*)d_in[3];
    const float* tb1  = (const float*)d_in[4];
    const float* tW2  = (const float*)d_in[5];
    const float* tb2  = (const float*)d_in[6];
    const float* gW1  = (const float*)d_in[7];
    const float* ga1s = (const float*)d_in[8];
    const float* ga1d = (const float*)d_in[9];
    const float* gb1  = (const float*)d_in[10];
    const float* gW2  = (const float*)d_in[11];
    const float* ga2s = (const float*)d_in[12];
    const float* ga2d = (const float*)d_in[13];
    const float* gb2  = (const float*)d_in[14];
    const float* cW1  = (const float*)d_in[15];
    const float* cb1  = (const float*)d_in[16];
    const float* cW2  = (const float*)d_in[17];
    const float* cb2  = (const float*)d_in[18];

    int N = in_sizes[1] / 10;
    int E = in_sizes[2] / 2;

    float* fws   = (float*)d_ws;
    float* t_enc = fws;
    float* h1    = fws + (size_t)N * 64;
    float* out1  = fws + (size_t)N * 192;
    float* a1s   = fws + (size_t)N * 320;
    float* a1d   = fws + (size_t)N * 324;
    float* h2    = h1;      // reuse (h1 dead after k_g1b)
    float* a2s   = a1s;     // reuse
    float* a2d   = a1d;     // reuse
    float* gbuf  = out1;    // reuse (out1 dead after k_g2a)

    int* ib       = (int*)(fws + (size_t)N * 328);
    int* counts   = ib;
    int* rowptr   = ib + N;
    int* nxt      = ib + 2 * N + 1;
    int* partials = ib + 3 * N + 1;
    int* col      = ib + 3 * N + 1 + 128;

    hipMemsetAsync(counts, 0, (size_t)N * sizeof(int), stream);

    int NB = (N + 1023) / 1024;
    k_count  <<<(E + 255) / 256, 256, 0, stream>>>(ei, counts, E);
    k_scan1  <<<NB, 1024, 0, stream>>>(counts, rowptr, partials, N);
    k_scan2  <<<1, 64, 0, stream>>>(partials, NB);
    k_scan3  <<<(N + 1 + 255) / 256, 256, 0, stream>>>(rowptr, partials, nxt, N);
    k_scatter<<<(E + 255) / 256, 256, 0, stream>>>(ei, nxt, col, E);

    int nb4 = (N + 3) / 4;
    k_temporal<<<nb4, 256, 0, stream>>>(td, tW1, tb1, tW2, tb2, t_enc, N);
    k_g1a     <<<nb4, 256, 0, stream>>>(x, gW1, ga1s, ga1d, h1, a1s, a1d, N);
    k_g1b     <<<nb4, 256, 0, stream>>>(rowptr, col, h1, a1s, a1d, gb1, out1, N);
    k_g2a     <<<nb4, 256, 0, stream>>>(out1, gW2, ga2s, ga2d, h2, a2s, a2d, N);
    k_g2b     <<<nb4, 256, 0, stream>>>(rowptr, col, h2, a2s, a2d, gb2, gbuf, N);
    k_cls     <<<nb4, 256, 0, stream>>>(t_enc, gbuf, cW1, cb1, cW2, cb2, (float*)d_out, N);
}

// Round 2
// 869.720 us; speedup vs baseline: 1.0607x; 1.0607x over previous
//
#include <hip/hip_runtime.h>
#include <hip/hip_bf16.h>

#define DEV_INLINE __device__ __forceinline__

DEV_INLINE float lrelu(float v) { return fmaxf(v, 0.2f * v); }

// ---------------------------------------------------------------------------
// CSR build kernels
// ---------------------------------------------------------------------------
__global__ void k_count(const int* __restrict__ ei, int* __restrict__ counts, int E) {
    int e = blockIdx.x * blockDim.x + threadIdx.x;
    if (e < E) atomicAdd(&counts[ei[E + e]], 1);
}

__global__ __launch_bounds__(1024) void k_scan1(const int* __restrict__ counts,
                                                int* __restrict__ rowptr,
                                                int* __restrict__ partials, int N) {
    __shared__ int sd[1024];
    int li = threadIdx.x;
    int i  = blockIdx.x * 1024 + li;
    int v  = (i < N) ? counts[i] : 0;
    sd[li] = v;
    __syncthreads();
    for (int off = 1; off < 1024; off <<= 1) {
        int t = (li >= off) ? sd[li - off] : 0;
        __syncthreads();
        sd[li] += t;
        __syncthreads();
    }
    int inc = sd[li];
    if (i < N) rowptr[i + 1] = inc;
    if (li == 1023) partials[blockIdx.x] = inc;
}

__global__ void k_scan2(int* __restrict__ partials, int NB) {
    if (threadIdx.x == 0 && blockIdx.x == 0) {
        int run = 0;
        for (int b = 0; b < NB; ++b) { int t = partials[b]; partials[b] = run; run += t; }
    }
}

__global__ void k_scan3(int* __restrict__ rowptr, const int* __restrict__ partials,
                        int* __restrict__ nxt, int N) {
    int i = blockIdx.x * blockDim.x + threadIdx.x;
    if (i > N) return;
    int v;
    if (i == 0) { v = 0; rowptr[0] = 0; }
    else        { v = rowptr[i] + partials[(i - 1) >> 10]; rowptr[i] = v; }
    if (i < N) nxt[i] = v;
}

__global__ void k_scatter(const int* __restrict__ ei, int* __restrict__ nxt,
                          int* __restrict__ col, int E) {
    int e = blockIdx.x * blockDim.x + threadIdx.x;
    if (e < E) {
        int d   = ei[E + e];
        int pos = atomicAdd(&nxt[d], 1);
        col[pos] = ei[e];
    }
}

// ---------------------------------------------------------------------------
// Fold temporal layer-2 into classifier:  W2c = tW2 @ cW1[0:64,:],
// bc = tb2 @ cW1[0:64,:] + cb1   (mean/linear commute, exact)
// ---------------------------------------------------------------------------
__global__ void k_fuse(const float* __restrict__ tW2, const float* __restrict__ cW1,
                       const float* __restrict__ tb2, const float* __restrict__ cb1,
                       float* __restrict__ W2c, float* __restrict__ bc) {
    int gid = blockIdx.x * 256 + threadIdx.x;
    if (gid < 4096) {
        int i = gid >> 6, c = gid & 63;
        float s = 0.f;
#pragma unroll 8
        for (int k = 0; k < 64; ++k) s = fmaf(tW2[i * 64 + k], cW1[k * 64 + c], s);
        W2c[gid] = s;
    } else if (gid < 4160) {
        int c = gid - 4096;
        float s = cb1[c];
#pragma unroll 8
        for (int k = 0; k < 64; ++k) s = fmaf(tb2[k], cW1[k * 64 + c], s);
        bc[c] = s;
    }
}

// ---------------------------------------------------------------------------
// Temporal encoder layer-1 + mean over T:  m = mean_t relu(x_t @ W1 + b1)
// lane = (cg, tg): cg = lane>>2 owns channels 4cg..4cg+3 (W1 cols in VGPRs),
// tg = lane&3 owns timesteps t = 4k+tg. Per-lane vector loads of x rows,
// quad shfl_xor reduce over tg. Two nodes per wave for ILP.
// ---------------------------------------------------------------------------
DEV_INLINE void row_fma(const float* __restrict__ r, const float4* __restrict__ w1,
                        const float4 b1, float4& acc) {
    float xv[10];
    *reinterpret_cast<float2*>(&xv[0]) = *reinterpret_cast<const float2*>(r);
    *reinterpret_cast<float2*>(&xv[2]) = *reinterpret_cast<const float2*>(r + 2);
    *reinterpret_cast<float2*>(&xv[4]) = *reinterpret_cast<const float2*>(r + 4);
    *reinterpret_cast<float2*>(&xv[6]) = *reinterpret_cast<const float2*>(r + 6);
    *reinterpret_cast<float2*>(&xv[8]) = *reinterpret_cast<const float2*>(r + 8);
    float4 u = b1;
#pragma unroll
    for (int i = 0; i < 10; ++i) {
        u.x = fmaf(xv[i], w1[i].x, u.x);
        u.y = fmaf(xv[i], w1[i].y, u.y);
        u.z = fmaf(xv[i], w1[i].z, u.z);
        u.w = fmaf(xv[i], w1[i].w, u.w);
    }
    acc.x += fmaxf(u.x, 0.f);
    acc.y += fmaxf(u.y, 0.f);
    acc.z += fmaxf(u.z, 0.f);
    acc.w += fmaxf(u.w, 0.f);
}

__global__ __launch_bounds__(256) void k_temporal(const float* __restrict__ td,
                                                  const float* __restrict__ tW1,
                                                  const float* __restrict__ tb1,
                                                  float* __restrict__ mbuf, int N) {
    int lane = threadIdx.x & 63;
    int wid  = (blockIdx.x * blockDim.x + threadIdx.x) >> 6;
    int nwav = (gridDim.x * blockDim.x) >> 6;
    int cg = lane >> 2, tg = lane & 3;

    float4 w1[10];
#pragma unroll
    for (int i = 0; i < 10; ++i) w1[i] = *reinterpret_cast<const float4*>(tW1 + i * 64 + cg * 4);
    float4 b1 = *reinterpret_cast<const float4*>(tb1 + cg * 4);

    for (long long p = wid; p * 2 < (long long)N; p += nwav) {
        int n0 = (int)(p * 2);
        int n1 = min(n0 + 1, N - 1);
        const float* pa = td + (size_t)n0 * 500;
        const float* pb = td + (size_t)n1 * 500;
        float4 aA = make_float4(0.f, 0.f, 0.f, 0.f);
        float4 aB = make_float4(0.f, 0.f, 0.f, 0.f);
#pragma unroll
        for (int k = 0; k < 12; ++k) {
            int t = 4 * k + tg;
            row_fma(pa + t * 10, w1, b1, aA);
            row_fma(pb + t * 10, w1, b1, aB);
        }
        if (tg < 2) {                       // t = 48+tg
            int t = 48 + tg;
            row_fma(pa + t * 10, w1, b1, aA);
            row_fma(pb + t * 10, w1, b1, aB);
        }
#define RED_Q(f) f += __shfl_xor(f, 1); f += __shfl_xor(f, 2);
        RED_Q(aA.x) RED_Q(aA.y) RED_Q(aA.z) RED_Q(aA.w)
        RED_Q(aB.x) RED_Q(aB.y) RED_Q(aB.z) RED_Q(aB.w)
#undef RED_Q
        if (tg == 0) {
            float4 mA = make_float4(aA.x * 0.02f, aA.y * 0.02f, aA.z * 0.02f, aA.w * 0.02f);
            float4 mB = make_float4(aB.x * 0.02f, aB.y * 0.02f, aB.z * 0.02f, aB.w * 0.02f);
            *reinterpret_cast<float4*>(mbuf + (size_t)n0 * 64 + cg * 4) = mA;
            *reinterpret_cast<float4*>(mbuf + (size_t)n1 * 64 + cg * 4) = mB;
        }
    }
}

// ---------------------------------------------------------------------------
// GATConv1 projection + attention scores. h1[n,128], a1s[n,4], a1d[n,4]
// ---------------------------------------------------------------------------
__global__ __launch_bounds__(256) void k_g1a(const float* __restrict__ x,
                                             const float* __restrict__ gW1,
                                             const float* __restrict__ as_w,
                                             const float* __restrict__ ad_w,
                                             float* __restrict__ h1,
                                             float* __restrict__ a1s,
                                             float* __restrict__ a1d, int N) {
    int tid = threadIdx.x, lane = tid & 63;
    int n0 = blockIdx.x * 4 + (tid >> 6);
    int n  = __builtin_amdgcn_readfirstlane(n0 < N ? n0 : N - 1);

    float wa[10], wb[10];
#pragma unroll
    for (int i = 0; i < 10; ++i) { wa[i] = gW1[i * 128 + lane]; wb[i] = gW1[i * 128 + 64 + lane]; }
    const float* xp = x + (size_t)n * 10;
    float ha = 0.f, hb = 0.f;
#pragma unroll
    for (int i = 0; i < 10; ++i) { float xv = xp[i]; ha = fmaf(xv, wa[i], ha); hb = fmaf(xv, wb[i], hb); }

    int c = lane & 31;
    int headA = lane >> 5;            // 0 or 1; second channel -> heads 2,3
    float ps_a = ha * as_w[headA * 32 + c];
    float ps_b = hb * as_w[(headA + 2) * 32 + c];
    float pd_a = ha * ad_w[headA * 32 + c];
    float pd_b = hb * ad_w[(headA + 2) * 32 + c];
#pragma unroll
    for (int m = 1; m < 32; m <<= 1) {
        ps_a += __shfl_xor(ps_a, m); ps_b += __shfl_xor(ps_b, m);
        pd_a += __shfl_xor(pd_a, m); pd_b += __shfl_xor(pd_b, m);
    }
    if (n0 < N) {
        h1[(size_t)n * 128 + lane]      = ha;
        h1[(size_t)n * 128 + 64 + lane] = hb;
        if (c == 0) {
            a1s[n * 4 + headA]     = ps_a;
            a1s[n * 4 + 2 + headA] = ps_b;
            a1d[n * 4 + headA]     = pd_a;
            a1d[n * 4 + 2 + headA] = pd_b;
        }
    }
}

// ---------------------------------------------------------------------------
// GATConv1 aggregation + bias + ELU. wave per dst node, lanes = channels.
// No max-shift: |logits| <~ 6, exp is safe in fp32 (softmax shift-invariant).
// ---------------------------------------------------------------------------
__global__ __launch_bounds__(256) void k_g1b(const int* __restrict__ rowptr,
                                             const int* __restrict__ col,
                                             const float* __restrict__ h1,
                                             const float* __restrict__ a1s,
                                             const float* __restrict__ a1d,
                                             const float* __restrict__ gb1,
                                             float* __restrict__ out1, int N) {
    int tid = threadIdx.x, lane = tid & 63;
    int n0 = blockIdx.x * 4 + (tid >> 6);
    int n  = __builtin_amdgcn_readfirstlane(n0 < N ? n0 : N - 1);

    int start = rowptr[n], end = rowptr[n + 1];
    const float4* a1s4 = reinterpret_cast<const float4*>(a1s);
    float4 adv = reinterpret_cast<const float4*>(a1d)[n];
    float4 asv = a1s4[n];

    // self loop
    float w0 = __expf(lrelu(asv.x + adv.x)), w1 = __expf(lrelu(asv.y + adv.y));
    float w2 = __expf(lrelu(asv.z + adv.z)), w3 = __expf(lrelu(asv.w + adv.w));
    float den0 = w0, den1 = w1, den2 = w2, den3 = w3;
    const float* hn = h1 + (size_t)n * 128;
    float acc1 = ((lane < 32) ? w0 : w1) * hn[lane];
    float acc2 = ((lane < 32) ? w2 : w3) * hn[64 + lane];

    for (int e = start; e < end; ++e) {
        int s = col[e];                       // loop-uniform -> scalar loads
        float4 q = a1s4[s];
        float e0 = __expf(lrelu(q.x + adv.x));
        float e1 = __expf(lrelu(q.y + adv.y));
        float e2 = __expf(lrelu(q.z + adv.z));
        float e3 = __expf(lrelu(q.w + adv.w));
        den0 += e0; den1 += e1; den2 += e2; den3 += e3;
        const float* hs = h1 + (size_t)s * 128;
        acc1 = fmaf((lane < 32) ? e0 : e1, hs[lane], acc1);
        acc2 = fmaf((lane < 32) ? e2 : e3, hs[64 + lane], acc2);
    }

    float v1 = acc1 / ((lane < 32) ? den0 : den1) + gb1[lane];
    float v2 = acc2 / ((lane < 32) ? den2 : den3) + gb1[64 + lane];
    v1 = (v1 > 0.f) ? v1 : (__expf(v1) - 1.f);   // ELU
    v2 = (v2 > 0.f) ? v2 : (__expf(v2) - 1.f);
    if (n0 < N) {
        out1[(size_t)n * 128 + lane]      = v1;
        out1[(size_t)n * 128 + 64 + lane] = v2;
    }
}

// ---------------------------------------------------------------------------
// GATConv2 projection (128->64) + attention scores
// ---------------------------------------------------------------------------
__global__ __launch_bounds__(256) void k_g2a(const float* __restrict__ out1,
                                             const float* __restrict__ gW2,
                                             const float* __restrict__ a2sw,
                                             const float* __restrict__ a2dw,
                                             float* __restrict__ h2,
                                             float* __restrict__ a2s,
                                             float* __restrict__ a2d, int N) {
    __shared__ float Ws[128 * 64];
    int tid = threadIdx.x, lane = tid & 63;
    for (int i = tid; i < 128 * 64; i += 256) Ws[i] = gW2[i];
    __syncthreads();
    int n0 = blockIdx.x * 4 + (tid >> 6);
    int n  = __builtin_amdgcn_readfirstlane(n0 < N ? n0 : N - 1);

    const float* xr = out1 + (size_t)n * 128;
    float acc = 0.f;
#pragma unroll
    for (int i0 = 0; i0 < 128; i0 += 8) {
        float xv[8];
#pragma unroll
        for (int k = 0; k < 8; ++k) xv[k] = xr[i0 + k];
#pragma unroll
        for (int k = 0; k < 8; ++k) acc = fmaf(xv[k], Ws[(i0 + k) * 64 + lane], acc);
    }
    float ps = acc * a2sw[lane], pd = acc * a2dw[lane];
#pragma unroll
    for (int msk = 1; msk < 64; msk <<= 1) { ps += __shfl_xor(ps, msk); pd += __shfl_xor(pd, msk); }
    if (n0 < N) {
        h2[(size_t)n * 64 + lane] = acc;
        if (lane == 0) { a2s[n] = ps; a2d[n] = pd; }
    }
}

// ---------------------------------------------------------------------------
// GATConv2 aggregation + bias. wave per dst node. No max-shift (safe, see g1b).
// ---------------------------------------------------------------------------
__global__ __launch_bounds__(256) void k_g2b(const int* __restrict__ rowptr,
                                             const int* __restrict__ col,
                                             const float* __restrict__ h2,
                                             const float* __restrict__ a2s,
                                             const float* __restrict__ a2d,
                                             const float* __restrict__ gb2,
                                             float* __restrict__ g, int N) {
    int tid = threadIdx.x, lane = tid & 63;
    int n0 = blockIdx.x * 4 + (tid >> 6);
    int n  = __builtin_amdgcn_readfirstlane(n0 < N ? n0 : N - 1);

    int start = rowptr[n], end = rowptr[n + 1];
    float ad  = a2d[n];
    float w   = __expf(lrelu(a2s[n] + ad));     // self loop
    float den = w;
    float acc = w * h2[(size_t)n * 64 + lane];
    for (int e = start; e < end; ++e) {
        int s = col[e];
        float wv = __expf(lrelu(a2s[s] + ad));
        den += wv;
        acc = fmaf(wv, h2[(size_t)s * 64 + lane], acc);
    }
    if (n0 < N) g[(size_t)n * 64 + lane] = acc / den + gb2[lane];
}

// ---------------------------------------------------------------------------
// Classifier with fused temporal layer-2:
// sigmoid(relu(m @ W2c + g @ cW1[64:] + bc) @ cW2 + cb2)
// ---------------------------------------------------------------------------
__global__ __launch_bounds__(256) void k_cls(const float* __restrict__ m,
                                             const float* __restrict__ g,
                                             const float* __restrict__ W2c,
                                             const float* __restrict__ cW1,
                                             const float* __restrict__ bc,
                                             const float* __restrict__ cW2,
                                             const float* __restrict__ cb2,
                                             float* __restrict__ out, int N) {
    __shared__ float Ws[128 * 64];
    int tid = threadIdx.x, lane = tid & 63;
    for (int i = tid; i < 128 * 64; i += 256) Ws[i] = (i < 4096) ? W2c[i] : cW1[i];
    __syncthreads();
    int n0 = blockIdx.x * 4 + (tid >> 6);
    int n  = __builtin_amdgcn_readfirstlane(n0 < N ? n0 : N - 1);

    const float* tp = m + (size_t)n * 64;
    const float* gp = g + (size_t)n * 64;
    float acc = bc[lane];
#pragma unroll
    for (int i0 = 0; i0 < 64; i0 += 8) {
        float xv[8];
#pragma unroll
        for (int k = 0; k < 8; ++k) xv[k] = tp[i0 + k];
#pragma unroll
        for (int k = 0; k < 8; ++k) acc = fmaf(xv[k], Ws[(i0 + k) * 64 + lane], acc);
    }
#pragma unroll
    for (int i0 = 0; i0 < 64; i0 += 8) {
        float xv[8];
#pragma unroll
        for (int k = 0; k < 8; ++k) xv[k] = gp[i0 + k];
#pragma unroll
        for (int k = 0; k < 8; ++k) acc = fmaf(xv[k], Ws[(64 + i0 + k) * 64 + lane], acc);
    }
    acc = fmaxf(acc, 0.f);
    float p = acc * cW2[lane];
#pragma unroll
    for (int msk = 1; msk < 64; msk <<= 1) p += __shfl_xor(p, msk);
    if (n0 < N && lane == 0) out[n] = 1.f / (1.f + __expf(-(p + cb2[0])));
}

// ---------------------------------------------------------------------------
extern "C" void kernel_launch(void* const* d_in, const int* in_sizes, int n_in,
                              void* d_out, int out_size, void* d_ws, size_t ws_size,
                              hipStream_t stream) {
    const float* td   = (const float*)d_in[0];
    const float* x    = (const float*)d_in[1];
    const int*   ei   = (const int*)d_in[2];
    const float* tW1  = (const float*)d_in[3];
    const float* tb1  = (const float*)d_in[4];
    const float* tW2  = (const float*)d_in[5];
    const float* tb2  = (const float*)d_in[6];
    const float* gW1  = (const float*)d_in[7];
    const float* ga1s = (const float*)d_in[8];
    const float* ga1d = (const float*)d_in[9];
    const float* gb1  = (const float*)d_in[10];
    const float* gW2  = (const float*)d_in[11];
    const float* ga2s = (const float*)d_in[12];
    const float* ga2d = (const float*)d_in[13];
    const float* gb2  = (const float*)d_in[14];
    const float* cW1  = (const float*)d_in[15];
    const float* cb1  = (const float*)d_in[16];
    const float* cW2  = (const float*)d_in[17];
    const float* cb2  = (const float*)d_in[18];

    int N = in_sizes[1] / 10;
    int E = in_sizes[2] / 2;

    float* fws   = (float*)d_ws;
    float* mbuf  = fws;                          // [N,64] post-mean hidden
    float* h1    = fws + (size_t)N * 64;
    float* out1  = fws + (size_t)N * 192;
    float* a1s   = fws + (size_t)N * 320;
    float* a1d   = fws + (size_t)N * 324;
    float* h2    = h1;      // reuse (h1 dead after k_g1b)
    float* a2s   = a1s;     // reuse
    float* a2d   = a1d;     // reuse
    float* gbuf  = out1;    // reuse (out1 dead after k_g2a)

    int* ib       = (int*)(fws + (size_t)N * 328);
    int* counts   = ib;
    int* rowptr   = ib + N;
    int* nxt      = ib + 2 * N + 1;
    int* partials = ib + 3 * N + 1;
    int* col      = ib + 3 * N + 1 + 128;

    // fused classifier weights overlay the nxt region (dead after k_scatter)
    float* W2c = (float*)nxt;
    float* bcf = W2c + 4096;

    hipMemsetAsync(counts, 0, (size_t)N * sizeof(int), stream);

    int NB = (N + 1023) / 1024;
    k_count  <<<(E + 255) / 256, 256, 0, stream>>>(ei, counts, E);
    k_scan1  <<<NB, 1024, 0, stream>>>(counts, rowptr, partials, N);
    k_scan2  <<<1, 64, 0, stream>>>(partials, NB);
    k_scan3  <<<(N + 1 + 255) / 256, 256, 0, stream>>>(rowptr, partials, nxt, N);
    k_scatter<<<(E + 255) / 256, 256, 0, stream>>>(ei, nxt, col, E);
    k_fuse   <<<17, 256, 0, stream>>>(tW2, cW1, tb2, cb1, W2c, bcf);

    int nb4 = (N + 3) / 4;
    k_temporal<<<1024, 256, 0, stream>>>(td, tW1, tb1, mbuf, N);
    k_g1a     <<<nb4, 256, 0, stream>>>(x, gW1, ga1s, ga1d, h1, a1s, a1d, N);
    k_g1b     <<<nb4, 256, 0, stream>>>(rowptr, col, h1, a1s, a1d, gb1, out1, N);
    k_g2a     <<<nb4, 256, 0, stream>>>(out1, gW2, ga2s, ga2d, h2, a2s, a2d, N);
    k_g2b     <<<nb4, 256, 0, stream>>>(rowptr, col, h2, a2s, a2d, gb2, gbuf, N);
    k_cls     <<<nb4, 256, 0, stream>>>(mbuf, gbuf, W2c, cW1, bcf, cW2, cb2, (float*)d_out, N);
}

// Round 3
// 719.030 us; speedup vs baseline: 1.2830x; 1.2096x over previous
//
#include <hip/hip_runtime.h>
#include <hip/hip_bf16.h>

#define DEV_INLINE __device__ __forceinline__

typedef __attribute__((ext_vector_type(8))) short short8v;
typedef __attribute__((ext_vector_type(4))) float f32x4;

DEV_INLINE float lrelu(float v) { return fmaxf(v, 0.2f * v); }

DEV_INLINE unsigned int cvt_pk_bf16(float lo, float hi) {
    unsigned int r;
    asm("v_cvt_pk_bf16_f32 %0, %1, %2" : "=v"(r) : "v"(lo), "v"(hi));
    return r;
}

DEV_INLINE unsigned short f2bf_rne(float f) {
    unsigned int b = __float_as_uint(f);
    return (unsigned short)((b + 0x7FFFu + ((b >> 16) & 1u)) >> 16);
}

// ---------------------------------------------------------------------------
// CSR build kernels
// ---------------------------------------------------------------------------
__global__ void k_count(const int* __restrict__ ei, int* __restrict__ counts, int E) {
    int e = blockIdx.x * blockDim.x + threadIdx.x;
    if (e < E) atomicAdd(&counts[ei[E + e]], 1);
}

__global__ __launch_bounds__(1024) void k_scan1(const int* __restrict__ counts,
                                                int* __restrict__ rowptr,
                                                int* __restrict__ partials, int N) {
    __shared__ int sd[1024];
    int li = threadIdx.x;
    int i  = blockIdx.x * 1024 + li;
    int v  = (i < N) ? counts[i] : 0;
    sd[li] = v;
    __syncthreads();
    for (int off = 1; off < 1024; off <<= 1) {
        int t = (li >= off) ? sd[li - off] : 0;
        __syncthreads();
        sd[li] += t;
        __syncthreads();
    }
    int inc = sd[li];
    if (i < N) rowptr[i + 1] = inc;
    if (li == 1023) partials[blockIdx.x] = inc;
}

__global__ void k_scan2(int* __restrict__ partials, int NB) {
    if (threadIdx.x == 0 && blockIdx.x == 0) {
        int run = 0;
        for (int b = 0; b < NB; ++b) { int t = partials[b]; partials[b] = run; run += t; }
    }
}

__global__ void k_scan3(int* __restrict__ rowptr, const int* __restrict__ partials,
                        int* __restrict__ nxt, int N) {
    int i = blockIdx.x * blockDim.x + threadIdx.x;
    if (i > N) return;
    int v;
    if (i == 0) { v = 0; rowptr[0] = 0; }
    else        { v = rowptr[i] + partials[(i - 1) >> 10]; rowptr[i] = v; }
    if (i < N) nxt[i] = v;
}

__global__ void k_scatter(const int* __restrict__ ei, int* __restrict__ nxt,
                          int* __restrict__ col, int E) {
    int e = blockIdx.x * blockDim.x + threadIdx.x;
    if (e < E) {
        int d   = ei[E + e];
        int pos = atomicAdd(&nxt[d], 1);
        col[pos] = ei[e];
    }
}

// ---------------------------------------------------------------------------
// Fold temporal layer-2 into classifier:  W2c = tW2 @ cW1[0:64,:],
// bc = tb2 @ cW1[0:64,:] + cb1   (mean/linear commute, exact)
// ---------------------------------------------------------------------------
__global__ void k_fuse(const float* __restrict__ tW2, const float* __restrict__ cW1,
                       const float* __restrict__ tb2, const float* __restrict__ cb1,
                       float* __restrict__ W2c, float* __restrict__ bc) {
    int gid = blockIdx.x * 256 + threadIdx.x;
    if (gid < 4096) {
        int i = gid >> 6, c = gid & 63;
        float s = 0.f;
#pragma unroll 8
        for (int k = 0; k < 64; ++k) s = fmaf(tW2[i * 64 + k], cW1[k * 64 + c], s);
        W2c[gid] = s;
    } else if (gid < 4160) {
        int c = gid - 4096;
        float s = cb1[c];
#pragma unroll 8
        for (int k = 0; k < 64; ++k) s = fmaf(tb2[k], cW1[k * 64 + c], s);
        bc[c] = s;
    }
}

// ---------------------------------------------------------------------------
// Temporal encoder layer-1 + mean over T, via MFMA 16x16x32 bf16.
// m[n,c] = (1/50) sum_t relu(x[n,t,:] @ W1[:,c] + b1[c])
// A tile: rows = 16 timesteps (4 tiles cover t=0..63, pad), K = 10 feats +
// bias slot k=10 (A has 1.0 there for valid rows -> invalid rows give
// relu(0)=0, no epilogue masking). B[cb]: cols = 16 channels per block.
// C/D layout: col=lane&15, row=(lane>>4)*4+i  [guide m89].
// ---------------------------------------------------------------------------
__global__ __launch_bounds__(256) void k_temporal(const float* __restrict__ td,
                                                  const float* __restrict__ tW1,
                                                  const float* __restrict__ tb1,
                                                  float* __restrict__ mbuf, int N) {
    int lane = threadIdx.x & 63;
    int wid  = (blockIdx.x * blockDim.x + threadIdx.x) >> 6;
    int nwav = (gridDim.x * blockDim.x) >> 6;
    int col  = lane & 15;
    int g    = lane >> 4;

    // B-frags: lane holds B[k][c], c = cb*16 + (lane&15), k = g*8 + j
    short8v B[4];
#pragma unroll
    for (int cb = 0; cb < 4; ++cb) {
        union { short8v v; unsigned short u[8]; } bu;
#pragma unroll
        for (int j = 0; j < 8; ++j) {
            int f = g * 8 + j;
            int c = cb * 16 + col;
            float w = (f < 10) ? tW1[f * 64 + c] : ((f == 10) ? tb1[c] : 0.f);
            bu.u[j] = f2bf_rne(w);
        }
        B[cb] = bu.v;
    }

    for (int n = wid; n < N; n += nwav) {
        const float* base = td + (size_t)n * 500;
        float sum0 = 0.f, sum1 = 0.f, sum2 = 0.f, sum3 = 0.f;
#pragma unroll
        for (int tt = 0; tt < 4; ++tt) {
            int t = tt * 16 + col;               // A row -> timestep
            float x0 = 0.f, x1 = 0.f, x2 = 0.f, x3 = 0.f;
            float x4 = 0.f, x5 = 0.f, x6 = 0.f, x7 = 0.f;
            bool valid = (t < 50);
            const float* rp = base + t * 10;
            if (g == 0 && valid) {               // k = 0..7 -> feats 0..7
                float2 p0 = *reinterpret_cast<const float2*>(rp);
                float2 p1 = *reinterpret_cast<const float2*>(rp + 2);
                float2 p2 = *reinterpret_cast<const float2*>(rp + 4);
                float2 p3 = *reinterpret_cast<const float2*>(rp + 6);
                x0 = p0.x; x1 = p0.y; x2 = p1.x; x3 = p1.y;
                x4 = p2.x; x5 = p2.y; x6 = p3.x; x7 = p3.y;
            } else if (g == 1 && valid) {        // k = 8..15 -> feats 8,9 + bias-1
                float2 p4 = *reinterpret_cast<const float2*>(rp + 8);
                x0 = p4.x; x1 = p4.y; x2 = 1.0f;
            }
            union { short8v v; unsigned int w[4]; } au;
            au.w[0] = cvt_pk_bf16(x0, x1);
            au.w[1] = cvt_pk_bf16(x2, x3);
            au.w[2] = cvt_pk_bf16(x4, x5);
            au.w[3] = cvt_pk_bf16(x6, x7);

            f32x4 z = {0.f, 0.f, 0.f, 0.f};
            f32x4 c0 = __builtin_amdgcn_mfma_f32_16x16x32_bf16(au.v, B[0], z, 0, 0, 0);
            f32x4 c1 = __builtin_amdgcn_mfma_f32_16x16x32_bf16(au.v, B[1], z, 0, 0, 0);
            f32x4 c2 = __builtin_amdgcn_mfma_f32_16x16x32_bf16(au.v, B[2], z, 0, 0, 0);
            f32x4 c3 = __builtin_amdgcn_mfma_f32_16x16x32_bf16(au.v, B[3], z, 0, 0, 0);
#pragma unroll
            for (int i = 0; i < 4; ++i) {
                sum0 += fmaxf(c0[i], 0.f);
                sum1 += fmaxf(c1[i], 0.f);
                sum2 += fmaxf(c2[i], 0.f);
                sum3 += fmaxf(c3[i], 0.f);
            }
        }
        // per-lane sums cover rows (g*4..g*4+3) of each tile; combine over g
        sum0 += __shfl_xor(sum0, 16); sum0 += __shfl_xor(sum0, 32);
        sum1 += __shfl_xor(sum1, 16); sum1 += __shfl_xor(sum1, 32);
        sum2 += __shfl_xor(sum2, 16); sum2 += __shfl_xor(sum2, 32);
        sum3 += __shfl_xor(sum3, 16); sum3 += __shfl_xor(sum3, 32);
        float v = (g == 0) ? sum0 : (g == 1) ? sum1 : (g == 2) ? sum2 : sum3;
        mbuf[(size_t)n * 64 + lane] = v * 0.02f;   // c = g*16 + col = lane
    }
}

// ---------------------------------------------------------------------------
// GATConv1 projection + attention scores. h1[n,128], a1s[n,4], a1d[n,4]
// ---------------------------------------------------------------------------
__global__ __launch_bounds__(256) void k_g1a(const float* __restrict__ x,
                                             const float* __restrict__ gW1,
                                             const float* __restrict__ as_w,
                                             const float* __restrict__ ad_w,
                                             float* __restrict__ h1,
                                             float* __restrict__ a1s,
                                             float* __restrict__ a1d, int N) {
    int tid = threadIdx.x, lane = tid & 63;
    int n0 = blockIdx.x * 4 + (tid >> 6);
    int n  = __builtin_amdgcn_readfirstlane(n0 < N ? n0 : N - 1);

    float wa[10], wb[10];
#pragma unroll
    for (int i = 0; i < 10; ++i) { wa[i] = gW1[i * 128 + lane]; wb[i] = gW1[i * 128 + 64 + lane]; }
    const float* xp = x + (size_t)n * 10;
    float ha = 0.f, hb = 0.f;
#pragma unroll
    for (int i = 0; i < 10; ++i) { float xv = xp[i]; ha = fmaf(xv, wa[i], ha); hb = fmaf(xv, wb[i], hb); }

    int c = lane & 31;
    int headA = lane >> 5;            // 0 or 1; second channel -> heads 2,3
    float ps_a = ha * as_w[headA * 32 + c];
    float ps_b = hb * as_w[(headA + 2) * 32 + c];
    float pd_a = ha * ad_w[headA * 32 + c];
    float pd_b = hb * ad_w[(headA + 2) * 32 + c];
#pragma unroll
    for (int m = 1; m < 32; m <<= 1) {
        ps_a += __shfl_xor(ps_a, m); ps_b += __shfl_xor(ps_b, m);
        pd_a += __shfl_xor(pd_a, m); pd_b += __shfl_xor(pd_b, m);
    }
    if (n0 < N) {
        h1[(size_t)n * 128 + lane]      = ha;
        h1[(size_t)n * 128 + 64 + lane] = hb;
        if (c == 0) {
            a1s[n * 4 + headA]     = ps_a;
            a1s[n * 4 + 2 + headA] = ps_b;
            a1d[n * 4 + headA]     = pd_a;
            a1d[n * 4 + 2 + headA] = pd_b;
        }
    }
}

// ---------------------------------------------------------------------------
// GATConv1 aggregation + bias + ELU. wave per dst node, lanes = channels.
// No max-shift (|logits| <~ 7, fp32 exp safe). 2-edge unroll for MLP.
// ---------------------------------------------------------------------------
__global__ __launch_bounds__(256) void k_g1b(const int* __restrict__ rowptr,
                                             const int* __restrict__ col,
                                             const float* __restrict__ h1,
                                             const float* __restrict__ a1s,
                                             const float* __restrict__ a1d,
                                             const float* __restrict__ gb1,
                                             float* __restrict__ out1, int N) {
    int tid = threadIdx.x, lane = tid & 63;
    int n0 = blockIdx.x * 4 + (tid >> 6);
    int n  = __builtin_amdgcn_readfirstlane(n0 < N ? n0 : N - 1);

    int start = rowptr[n], end = rowptr[n + 1];
    const float4* a1s4 = reinterpret_cast<const float4*>(a1s);
    float4 adv = reinterpret_cast<const float4*>(a1d)[n];
    float4 asv = a1s4[n];

    // self loop
    float w0 = __expf(lrelu(asv.x + adv.x)), w1 = __expf(lrelu(asv.y + adv.y));
    float w2 = __expf(lrelu(asv.z + adv.z)), w3 = __expf(lrelu(asv.w + adv.w));
    float den0 = w0, den1 = w1, den2 = w2, den3 = w3;
    const float* hn = h1 + (size_t)n * 128;
    float acc1 = ((lane < 32) ? w0 : w1) * hn[lane];
    float acc2 = ((lane < 32) ? w2 : w3) * hn[64 + lane];

    int e = start;
    for (; e + 2 <= end; e += 2) {
        int s0 = col[e], s1 = col[e + 1];
        float4 q0 = a1s4[s0];
        float4 q1 = a1s4[s1];
        float e00 = __expf(lrelu(q0.x + adv.x));
        float e01 = __expf(lrelu(q0.y + adv.y));
        float e02 = __expf(lrelu(q0.z + adv.z));
        float e03 = __expf(lrelu(q0.w + adv.w));
        float e10 = __expf(lrelu(q1.x + adv.x));
        float e11 = __expf(lrelu(q1.y + adv.y));
        float e12 = __expf(lrelu(q1.z + adv.z));
        float e13 = __expf(lrelu(q1.w + adv.w));
        den0 += e00 + e10; den1 += e01 + e11;
        den2 += e02 + e12; den3 += e03 + e13;
        const float* hs0 = h1 + (size_t)s0 * 128;
        const float* hs1 = h1 + (size_t)s1 * 128;
        acc1 = fmaf((lane < 32) ? e00 : e01, hs0[lane], acc1);
        acc2 = fmaf((lane < 32) ? e02 : e03, hs0[64 + lane], acc2);
        acc1 = fmaf((lane < 32) ? e10 : e11, hs1[lane], acc1);
        acc2 = fmaf((lane < 32) ? e12 : e13, hs1[64 + lane], acc2);
    }
    if (e < end) {
        int s = col[e];
        float4 q = a1s4[s];
        float e0 = __expf(lrelu(q.x + adv.x));
        float e1 = __expf(lrelu(q.y + adv.y));
        float e2 = __expf(lrelu(q.z + adv.z));
        float e3 = __expf(lrelu(q.w + adv.w));
        den0 += e0; den1 += e1; den2 += e2; den3 += e3;
        const float* hs = h1 + (size_t)s * 128;
        acc1 = fmaf((lane < 32) ? e0 : e1, hs[lane], acc1);
        acc2 = fmaf((lane < 32) ? e2 : e3, hs[64 + lane], acc2);
    }

    float v1 = acc1 / ((lane < 32) ? den0 : den1) + gb1[lane];
    float v2 = acc2 / ((lane < 32) ? den2 : den3) + gb1[64 + lane];
    v1 = (v1 > 0.f) ? v1 : (__expf(v1) - 1.f);   // ELU
    v2 = (v2 > 0.f) ? v2 : (__expf(v2) - 1.f);
    if (n0 < N) {
        out1[(size_t)n * 128 + lane]      = v1;
        out1[(size_t)n * 128 + 64 + lane] = v2;
    }
}

// ---------------------------------------------------------------------------
// GATConv2 projection (128->64) + attention scores
// ---------------------------------------------------------------------------
__global__ __launch_bounds__(256) void k_g2a(const float* __restrict__ out1,
                                             const float* __restrict__ gW2,
                                             const float* __restrict__ a2sw,
                                             const float* __restrict__ a2dw,
                                             float* __restrict__ h2,
                                             float* __restrict__ a2s,
                                             float* __restrict__ a2d, int N) {
    __shared__ float Ws[128 * 64];
    int tid = threadIdx.x, lane = tid & 63;
    for (int i = tid; i < 128 * 64; i += 256) Ws[i] = gW2[i];
    __syncthreads();
    int n0 = blockIdx.x * 4 + (tid >> 6);
    int n  = __builtin_amdgcn_readfirstlane(n0 < N ? n0 : N - 1);

    const float* xr = out1 + (size_t)n * 128;
    float acc = 0.f;
#pragma unroll
    for (int i0 = 0; i0 < 128; i0 += 8) {
        float xv[8];
#pragma unroll
        for (int k = 0; k < 8; ++k) xv[k] = xr[i0 + k];
#pragma unroll
        for (int k = 0; k < 8; ++k) acc = fmaf(xv[k], Ws[(i0 + k) * 64 + lane], acc);
    }
    float ps = acc * a2sw[lane], pd = acc * a2dw[lane];
#pragma unroll
    for (int msk = 1; msk < 64; msk <<= 1) { ps += __shfl_xor(ps, msk); pd += __shfl_xor(pd, msk); }
    if (n0 < N) {
        h2[(size_t)n * 64 + lane] = acc;
        if (lane == 0) { a2s[n] = ps; a2d[n] = pd; }
    }
}

// ---------------------------------------------------------------------------
// GATConv2 aggregation + bias. wave per dst node. 2-edge unroll.
// ---------------------------------------------------------------------------
__global__ __launch_bounds__(256) void k_g2b(const int* __restrict__ rowptr,
                                             const int* __restrict__ col,
                                             const float* __restrict__ h2,
                                             const float* __restrict__ a2s,
                                             const float* __restrict__ a2d,
                                             const float* __restrict__ gb2,
                                             float* __restrict__ g, int N) {
    int tid = threadIdx.x, lane = tid & 63;
    int n0 = blockIdx.x * 4 + (tid >> 6);
    int n  = __builtin_amdgcn_readfirstlane(n0 < N ? n0 : N - 1);

    int start = rowptr[n], end = rowptr[n + 1];
    float ad  = a2d[n];
    float w   = __expf(lrelu(a2s[n] + ad));     // self loop
    float den = w;
    float acc = w * h2[(size_t)n * 64 + lane];
    int e = start;
    for (; e + 2 <= end; e += 2) {
        int s0 = col[e], s1 = col[e + 1];
        float w0 = __expf(lrelu(a2s[s0] + ad));
        float w1v = __expf(lrelu(a2s[s1] + ad));
        den += w0 + w1v;
        acc = fmaf(w0, h2[(size_t)s0 * 64 + lane], acc);
        acc = fmaf(w1v, h2[(size_t)s1 * 64 + lane], acc);
    }
    if (e < end) {
        int s = col[e];
        float wv = __expf(lrelu(a2s[s] + ad));
        den += wv;
        acc = fmaf(wv, h2[(size_t)s * 64 + lane], acc);
    }
    if (n0 < N) g[(size_t)n * 64 + lane] = acc / den + gb2[lane];
}

// ---------------------------------------------------------------------------
// Classifier with fused temporal layer-2:
// sigmoid(relu(m @ W2c + g @ cW1[64:] + bc) @ cW2 + cb2)
// ---------------------------------------------------------------------------
__global__ __launch_bounds__(256) void k_cls(const float* __restrict__ m,
                                             const float* __restrict__ g,
                                             const float* __restrict__ W2c,
                                             const float* __restrict__ cW1,
                                             const float* __restrict__ bc,
                                             const float* __restrict__ cW2,
                                             const float* __restrict__ cb2,
                                             float* __restrict__ out, int N) {
    __shared__ float Ws[128 * 64];
    int tid = threadIdx.x, lane = tid & 63;
    for (int i = tid; i < 128 * 64; i += 256) Ws[i] = (i < 4096) ? W2c[i] : cW1[i];
    __syncthreads();
    int n0 = blockIdx.x * 4 + (tid >> 6);
    int n  = __builtin_amdgcn_readfirstlane(n0 < N ? n0 : N - 1);

    const float* tp = m + (size_t)n * 64;
    const float* gp = g + (size_t)n * 64;
    float acc = bc[lane];
#pragma unroll
    for (int i0 = 0; i0 < 64; i0 += 8) {
        float xv[8];
#pragma unroll
        for (int k = 0; k < 8; ++k) xv[k] = tp[i0 + k];
#pragma unroll
        for (int k = 0; k < 8; ++k) acc = fmaf(xv[k], Ws[(i0 + k) * 64 + lane], acc);
    }
#pragma unroll
    for (int i0 = 0; i0 < 64; i0 += 8) {
        float xv[8];
#pragma unroll
        for (int k = 0; k < 8; ++k) xv[k] = gp[i0 + k];
#pragma unroll
        for (int k = 0; k < 8; ++k) acc = fmaf(xv[k], Ws[(64 + i0 + k) * 64 + lane], acc);
    }
    acc = fmaxf(acc, 0.f);
    float p = acc * cW2[lane];
#pragma unroll
    for (int msk = 1; msk < 64; msk <<= 1) p += __shfl_xor(p, msk);
    if (n0 < N && lane == 0) out[n] = 1.f / (1.f + __expf(-(p + cb2[0])));
}

// ---------------------------------------------------------------------------
extern "C" void kernel_launch(void* const* d_in, const int* in_sizes, int n_in,
                              void* d_out, int out_size, void* d_ws, size_t ws_size,
                              hipStream_t stream) {
    const float* td   = (const float*)d_in[0];
    const float* x    = (const float*)d_in[1];
    const int*   ei   = (const int*)d_in[2];
    const float* tW1  = (const float*)d_in[3];
    const float* tb1  = (const float*)d_in[4];
    const float* tW2  = (const float*)d_in[5];
    const float* tb2  = (const float*)d_in[6];
    const float* gW1  = (const float*)d_in[7];
    const float* ga1s = (const float*)d_in[8];
    const float* ga1d = (const float*)d_in[9];
    const float* gb1  = (const float*)d_in[10];
    const float* gW2  = (const float*)d_in[11];
    const float* ga2s = (const float*)d_in[12];
    const float* ga2d = (const float*)d_in[13];
    const float* gb2  = (const float*)d_in[14];
    const float* cW1  = (const float*)d_in[15];
    const float* cb1  = (const float*)d_in[16];
    const float* cW2  = (const float*)d_in[17];
    const float* cb2  = (const float*)d_in[18];

    int N = in_sizes[1] / 10;
    int E = in_sizes[2] / 2;

    float* fws   = (float*)d_ws;
    float* mbuf  = fws;                          // [N,64] post-mean hidden
    float* h1    = fws + (size_t)N * 64;
    float* out1  = fws + (size_t)N * 192;
    float* a1s   = fws + (size_t)N * 320;
    float* a1d   = fws + (size_t)N * 324;
    float* h2    = h1;      // reuse (h1 dead after k_g1b)
    float* a2s   = a1s;     // reuse
    float* a2d   = a1d;     // reuse
    float* gbuf  = out1;    // reuse (out1 dead after k_g2a)

    int* ib       = (int*)(fws + (size_t)N * 328);
    int* counts   = ib;
    int* rowptr   = ib + N;
    int* nxt      = ib + 2 * N + 1;
    int* partials = ib + 3 * N + 1;
    int* col      = ib + 3 * N + 1 + 128;

    // fused classifier weights overlay the nxt region (dead after k_scatter)
    float* W2c = (float*)nxt;
    float* bcf = W2c + 4096;

    hipMemsetAsync(counts, 0, (size_t)N * sizeof(int), stream);

    int NB = (N + 1023) / 1024;
    k_count  <<<(E + 255) / 256, 256, 0, stream>>>(ei, counts, E);
    k_scan1  <<<NB, 1024, 0, stream>>>(counts, rowptr, partials, N);
    k_scan2  <<<1, 64, 0, stream>>>(partials, NB);
    k_scan3  <<<(N + 1 + 255) / 256, 256, 0, stream>>>(rowptr, partials, nxt, N);
    k_scatter<<<(E + 255) / 256, 256, 0, stream>>>(ei, nxt, col, E);
    k_fuse   <<<17, 256, 0, stream>>>(tW2, cW1, tb2, cb1, W2c, bcf);

    int nb4 = (N + 3) / 4;
    k_temporal<<<2048, 256, 0, stream>>>(td, tW1, tb1, mbuf, N);
    k_g1a     <<<nb4, 256, 0, stream>>>(x, gW1, ga1s, ga1d, h1, a1s, a1d, N);
    k_g1b     <<<nb4, 256, 0, stream>>>(rowptr, col, h1, a1s, a1d, gb1, out1, N);
    k_g2a     <<<nb4, 256, 0, stream>>>(out1, gW2, ga2s, ga2d, h2, a2s, a2d, N);
    k_g2b     <<<nb4, 256, 0, stream>>>(rowptr, col, h2, a2s, a2d, gb2, gbuf, N);
    k_cls     <<<nb4, 256, 0, stream>>>(mbuf, gbuf, W2c, cW1, bcf, cW2, cb2, (float*)d_out, N);
}

// Round 4
// 715.751 us; speedup vs baseline: 1.2889x; 1.0046x over previous
//
#include <hip/hip_runtime.h>
#include <hip/hip_bf16.h>

#define DEV_INLINE __device__ __forceinline__

typedef __attribute__((ext_vector_type(8))) short short8v;
typedef __attribute__((ext_vector_type(4))) float f32x4;

DEV_INLINE float lrelu(float v) { return fmaxf(v, 0.2f * v); }

DEV_INLINE unsigned int cvt_pk_bf16(float lo, float hi) {
    unsigned int r;
    asm("v_cvt_pk_bf16_f32 %0, %1, %2" : "=v"(r) : "v"(lo), "v"(hi));
    return r;
}

DEV_INLINE unsigned short f2bf_rne(float f) {
    unsigned int b = __float_as_uint(f);
    return (unsigned short)((b + 0x7FFFu + ((b >> 16) & 1u)) >> 16);
}

DEV_INLINE float bf_lo(unsigned int u) { return __uint_as_float(u << 16); }
DEV_INLINE float bf_hi(unsigned int u) { return __uint_as_float(u & 0xFFFF0000u); }

// ---------------------------------------------------------------------------
// CSR build kernels
// ---------------------------------------------------------------------------
__global__ void k_count(const int* __restrict__ ei, int* __restrict__ counts, int E) {
    int e = blockIdx.x * blockDim.x + threadIdx.x;
    if (e < E) atomicAdd(&counts[ei[E + e]], 1);
}

__global__ __launch_bounds__(1024) void k_scan1(const int* __restrict__ counts,
                                                int* __restrict__ rowptr,
                                                int* __restrict__ partials, int N) {
    __shared__ int sd[1024];
    int li = threadIdx.x;
    int i  = blockIdx.x * 1024 + li;
    int v  = (i < N) ? counts[i] : 0;
    sd[li] = v;
    __syncthreads();
    for (int off = 1; off < 1024; off <<= 1) {
        int t = (li >= off) ? sd[li - off] : 0;
        __syncthreads();
        sd[li] += t;
        __syncthreads();
    }
    int inc = sd[li];
    if (i < N) rowptr[i + 1] = inc;
    if (li == 1023) partials[blockIdx.x] = inc;
}

__global__ void k_scan2(int* __restrict__ partials, int NB) {
    if (threadIdx.x == 0 && blockIdx.x == 0) {
        int run = 0;
        for (int b = 0; b < NB; ++b) { int t = partials[b]; partials[b] = run; run += t; }
    }
}

__global__ void k_scan3(int* __restrict__ rowptr, const int* __restrict__ partials,
                        int* __restrict__ nxt, int N) {
    int i = blockIdx.x * blockDim.x + threadIdx.x;
    if (i > N) return;
    int v;
    if (i == 0) { v = 0; rowptr[0] = 0; }
    else        { v = rowptr[i] + partials[(i - 1) >> 10]; rowptr[i] = v; }
    if (i < N) nxt[i] = v;
}

__global__ void k_scatter(const int* __restrict__ ei, int* __restrict__ nxt,
                          int* __restrict__ col, int E) {
    int e = blockIdx.x * blockDim.x + threadIdx.x;
    if (e < E) {
        int d   = ei[E + e];
        int pos = atomicAdd(&nxt[d], 1);
        col[pos] = ei[e];
    }
}

// ---------------------------------------------------------------------------
// Fold temporal layer-2 into classifier:  W2c = tW2 @ cW1[0:64,:],
// bc = tb2 @ cW1[0:64,:] + cb1   (mean/linear commute, exact)
// ---------------------------------------------------------------------------
__global__ void k_fuse(const float* __restrict__ tW2, const float* __restrict__ cW1,
                       const float* __restrict__ tb2, const float* __restrict__ cb1,
                       float* __restrict__ W2c, float* __restrict__ bc) {
    int gid = blockIdx.x * 256 + threadIdx.x;
    if (gid < 4096) {
        int i = gid >> 6, c = gid & 63;
        float s = 0.f;
#pragma unroll 8
        for (int k = 0; k < 64; ++k) s = fmaf(tW2[i * 64 + k], cW1[k * 64 + c], s);
        W2c[gid] = s;
    } else if (gid < 4160) {
        int c = gid - 4096;
        float s = cb1[c];
#pragma unroll 8
        for (int k = 0; k < 64; ++k) s = fmaf(tb2[k], cW1[k * 64 + c], s);
        bc[c] = s;
    }
}

// ---------------------------------------------------------------------------
// Temporal encoder layer-1 + mean over T, via MFMA 16x16x32 bf16.
// ---------------------------------------------------------------------------
__global__ __launch_bounds__(256) void k_temporal(const float* __restrict__ td,
                                                  const float* __restrict__ tW1,
                                                  const float* __restrict__ tb1,
                                                  float* __restrict__ mbuf, int N) {
    int lane = threadIdx.x & 63;
    int wid  = (blockIdx.x * blockDim.x + threadIdx.x) >> 6;
    int nwav = (gridDim.x * blockDim.x) >> 6;
    int col  = lane & 15;
    int g    = lane >> 4;

    short8v B[4];
#pragma unroll
    for (int cb = 0; cb < 4; ++cb) {
        union { short8v v; unsigned short u[8]; } bu;
#pragma unroll
        for (int j = 0; j < 8; ++j) {
            int f = g * 8 + j;
            int c = cb * 16 + col;
            float w = (f < 10) ? tW1[f * 64 + c] : ((f == 10) ? tb1[c] : 0.f);
            bu.u[j] = f2bf_rne(w);
        }
        B[cb] = bu.v;
    }

    for (int n = wid; n < N; n += nwav) {
        const float* base = td + (size_t)n * 500;
        float sum0 = 0.f, sum1 = 0.f, sum2 = 0.f, sum3 = 0.f;
#pragma unroll
        for (int tt = 0; tt < 4; ++tt) {
            int t = tt * 16 + col;
            float x0 = 0.f, x1 = 0.f, x2 = 0.f, x3 = 0.f;
            float x4 = 0.f, x5 = 0.f, x6 = 0.f, x7 = 0.f;
            bool valid = (t < 50);
            const float* rp = base + t * 10;
            if (g == 0 && valid) {
                float2 p0 = *reinterpret_cast<const float2*>(rp);
                float2 p1 = *reinterpret_cast<const float2*>(rp + 2);
                float2 p2 = *reinterpret_cast<const float2*>(rp + 4);
                float2 p3 = *reinterpret_cast<const float2*>(rp + 6);
                x0 = p0.x; x1 = p0.y; x2 = p1.x; x3 = p1.y;
                x4 = p2.x; x5 = p2.y; x6 = p3.x; x7 = p3.y;
            } else if (g == 1 && valid) {
                float2 p4 = *reinterpret_cast<const float2*>(rp + 8);
                x0 = p4.x; x1 = p4.y; x2 = 1.0f;
            }
            union { short8v v; unsigned int w[4]; } au;
            au.w[0] = cvt_pk_bf16(x0, x1);
            au.w[1] = cvt_pk_bf16(x2, x3);
            au.w[2] = cvt_pk_bf16(x4, x5);
            au.w[3] = cvt_pk_bf16(x6, x7);

            f32x4 z = {0.f, 0.f, 0.f, 0.f};
            f32x4 c0 = __builtin_amdgcn_mfma_f32_16x16x32_bf16(au.v, B[0], z, 0, 0, 0);
            f32x4 c1 = __builtin_amdgcn_mfma_f32_16x16x32_bf16(au.v, B[1], z, 0, 0, 0);
            f32x4 c2 = __builtin_amdgcn_mfma_f32_16x16x32_bf16(au.v, B[2], z, 0, 0, 0);
            f32x4 c3 = __builtin_amdgcn_mfma_f32_16x16x32_bf16(au.v, B[3], z, 0, 0, 0);
#pragma unroll
            for (int i = 0; i < 4; ++i) {
                sum0 += fmaxf(c0[i], 0.f);
                sum1 += fmaxf(c1[i], 0.f);
                sum2 += fmaxf(c2[i], 0.f);
                sum3 += fmaxf(c3[i], 0.f);
            }
        }
        sum0 += __shfl_xor(sum0, 16); sum0 += __shfl_xor(sum0, 32);
        sum1 += __shfl_xor(sum1, 16); sum1 += __shfl_xor(sum1, 32);
        sum2 += __shfl_xor(sum2, 16); sum2 += __shfl_xor(sum2, 32);
        sum3 += __shfl_xor(sum3, 16); sum3 += __shfl_xor(sum3, 32);
        float v = (g == 0) ? sum0 : (g == 1) ? sum1 : (g == 2) ? sum2 : sum3;
        mbuf[(size_t)n * 64 + lane] = v * 0.02f;
    }
}

// ---------------------------------------------------------------------------
// GATConv1 projection + attention scores. h1b bf16 [n,128], a1s/a1d fp32 [n,4]
// ---------------------------------------------------------------------------
__global__ __launch_bounds__(256) void k_g1a(const float* __restrict__ x,
                                             const float* __restrict__ gW1,
                                             const float* __restrict__ as_w,
                                             const float* __restrict__ ad_w,
                                             unsigned short* __restrict__ h1b,
                                             float* __restrict__ a1s,
                                             float* __restrict__ a1d, int N) {
    int tid = threadIdx.x, lane = tid & 63;
    int n0 = blockIdx.x * 4 + (tid >> 6);
    int n  = __builtin_amdgcn_readfirstlane(n0 < N ? n0 : N - 1);

    float wa[10], wb[10];
#pragma unroll
    for (int i = 0; i < 10; ++i) { wa[i] = gW1[i * 128 + lane]; wb[i] = gW1[i * 128 + 64 + lane]; }
    const float* xp = x + (size_t)n * 10;
    float ha = 0.f, hb = 0.f;
#pragma unroll
    for (int i = 0; i < 10; ++i) { float xv = xp[i]; ha = fmaf(xv, wa[i], ha); hb = fmaf(xv, wb[i], hb); }

    int c = lane & 31;
    int headA = lane >> 5;
    float ps_a = ha * as_w[headA * 32 + c];
    float ps_b = hb * as_w[(headA + 2) * 32 + c];
    float pd_a = ha * ad_w[headA * 32 + c];
    float pd_b = hb * ad_w[(headA + 2) * 32 + c];
#pragma unroll
    for (int m = 1; m < 32; m <<= 1) {
        ps_a += __shfl_xor(ps_a, m); ps_b += __shfl_xor(ps_b, m);
        pd_a += __shfl_xor(pd_a, m); pd_b += __shfl_xor(pd_b, m);
    }
    if (n0 < N) {
        h1b[(size_t)n * 128 + lane]      = f2bf_rne(ha);
        h1b[(size_t)n * 128 + 64 + lane] = f2bf_rne(hb);
        if (c == 0) {
            a1s[n * 4 + headA]     = ps_a;
            a1s[n * 4 + 2 + headA] = ps_b;
            a1d[n * 4 + headA]     = pd_a;
            a1d[n * 4 + 2 + headA] = pd_b;
        }
    }
}

// ---------------------------------------------------------------------------
// GATConv1 aggregation + bias + ELU. wave per dst node. Lane l owns channels
// (2l, 2l+1) -> single head l>>4: ONE exp per lane per edge, per-lane dword
// loads of a1s[s*4+head] and packed-bf16 h1 pair. No max-shift (logits small).
// ---------------------------------------------------------------------------
__global__ __launch_bounds__(256) void k_g1b(const int* __restrict__ rowptr,
                                             const int* __restrict__ col,
                                             const unsigned int* __restrict__ h1u,
                                             const float* __restrict__ a1s,
                                             const float* __restrict__ a1d,
                                             const float* __restrict__ gb1,
                                             float* __restrict__ out1, int N) {
    int tid = threadIdx.x, lane = tid & 63;
    int n0 = blockIdx.x * 4 + (tid >> 6);
    int n  = __builtin_amdgcn_readfirstlane(n0 < N ? n0 : N - 1);

    int start = rowptr[n], end = rowptr[n + 1];
    int hsel = lane >> 4;
    float advh = a1d[n * 4 + hsel];
    float gbl  = gb1[2 * lane];
    float gbh  = gb1[2 * lane + 1];

    // self loop
    float w  = __expf(lrelu(a1s[n * 4 + hsel] + advh));
    float den = w;
    unsigned int u = h1u[(size_t)n * 64 + lane];
    float accL = w * bf_lo(u), accH = w * bf_hi(u);

    int e = start;
    for (; e + 2 <= end; e += 2) {
        int s0 = col[e], s1 = col[e + 1];
        float q0 = a1s[s0 * 4 + hsel];
        float q1 = a1s[s1 * 4 + hsel];
        unsigned int u0 = h1u[(size_t)s0 * 64 + lane];
        unsigned int u1 = h1u[(size_t)s1 * 64 + lane];
        float w0 = __expf(lrelu(q0 + advh));
        float w1 = __expf(lrelu(q1 + advh));
        den += w0 + w1;
        accL = fmaf(w0, bf_lo(u0), accL);
        accH = fmaf(w0, bf_hi(u0), accH);
        accL = fmaf(w1, bf_lo(u1), accL);
        accH = fmaf(w1, bf_hi(u1), accH);
    }
    if (e < end) {
        int s = col[e];
        float q = a1s[s * 4 + hsel];
        unsigned int us = h1u[(size_t)s * 64 + lane];
        float ws = __expf(lrelu(q + advh));
        den += ws;
        accL = fmaf(ws, bf_lo(us), accL);
        accH = fmaf(ws, bf_hi(us), accH);
    }

    float inv = 1.f / den;
    float vL = accL * inv + gbl;
    float vH = accH * inv + gbh;
    vL = (vL > 0.f) ? vL : (__expf(vL) - 1.f);   // ELU
    vH = (vH > 0.f) ? vH : (__expf(vH) - 1.f);
    if (n0 < N)
        *reinterpret_cast<float2*>(out1 + (size_t)n * 128 + 2 * lane) = make_float2(vL, vH);
}

// ---------------------------------------------------------------------------
// GATConv2 projection (128->64) + attention scores; h2 stored packed bf16
// ---------------------------------------------------------------------------
__global__ __launch_bounds__(256) void k_g2a(const float* __restrict__ out1,
                                             const float* __restrict__ gW2,
                                             const float* __restrict__ a2sw,
                                             const float* __restrict__ a2dw,
                                             unsigned short* __restrict__ h2b,
                                             float* __restrict__ a2s,
                                             float* __restrict__ a2d, int N) {
    __shared__ float Ws[128 * 64];
    int tid = threadIdx.x, lane = tid & 63;
    for (int i = tid; i < 128 * 64; i += 256) Ws[i] = gW2[i];
    __syncthreads();
    int n0 = blockIdx.x * 4 + (tid >> 6);
    int n  = __builtin_amdgcn_readfirstlane(n0 < N ? n0 : N - 1);

    const float* xr = out1 + (size_t)n * 128;
    float acc = 0.f;
#pragma unroll
    for (int i0 = 0; i0 < 128; i0 += 8) {
        float xv[8];
#pragma unroll
        for (int k = 0; k < 8; ++k) xv[k] = xr[i0 + k];
#pragma unroll
        for (int k = 0; k < 8; ++k) acc = fmaf(xv[k], Ws[(i0 + k) * 64 + lane], acc);
    }
    float ps = acc * a2sw[lane], pd = acc * a2dw[lane];
#pragma unroll
    for (int msk = 1; msk < 64; msk <<= 1) { ps += __shfl_xor(ps, msk); pd += __shfl_xor(pd, msk); }
    if (n0 < N) {
        h2b[(size_t)n * 64 + lane] = f2bf_rne(acc);
        if (lane == 0) { a2s[n] = ps; a2d[n] = pd; }
    }
}

// ---------------------------------------------------------------------------
// GATConv2 aggregation + bias. Half-wave per edge: half h = lane>>5 processes
// edges start+2i+h; lane covers channels (2c,2c+1), c=lane&31, via packed bf16.
// Halves combined with shfl_xor(32).
// ---------------------------------------------------------------------------
__global__ __launch_bounds__(256) void k_g2b(const int* __restrict__ rowptr,
                                             const int* __restrict__ col,
                                             const unsigned int* __restrict__ h2u,
                                             const float* __restrict__ a2s,
                                             const float* __restrict__ a2d,
                                             const float* __restrict__ gb2,
                                             float* __restrict__ g, int N) {
    int tid = threadIdx.x, lane = tid & 63;
    int n0 = blockIdx.x * 4 + (tid >> 6);
    int n  = __builtin_amdgcn_readfirstlane(n0 < N ? n0 : N - 1);

    int start = rowptr[n], end = rowptr[n + 1];
    int h = lane >> 5, c = lane & 31;
    float ad = a2d[n];

    float den = 0.f, accL = 0.f, accH = 0.f;
    if (h == 0) {                                  // self loop on half 0
        float w = __expf(lrelu(a2s[n] + ad));
        unsigned int u = h2u[(size_t)n * 32 + c];
        den = w; accL = w * bf_lo(u); accH = w * bf_hi(u);
    }
    for (int e = start + h; e < end; e += 2) {
        int s = col[e];
        float w = __expf(lrelu(a2s[s] + ad));
        unsigned int u = h2u[(size_t)s * 32 + c];
        den += w;
        accL = fmaf(w, bf_lo(u), accL);
        accH = fmaf(w, bf_hi(u), accH);
    }
    den  += __shfl_xor(den, 32);
    accL += __shfl_xor(accL, 32);
    accH += __shfl_xor(accH, 32);

    if (n0 < N && h == 0) {
        float inv = 1.f / den;
        *reinterpret_cast<float2*>(g + (size_t)n * 64 + 2 * c) =
            make_float2(accL * inv + gb2[2 * c], accH * inv + gb2[2 * c + 1]);
    }
}

// ---------------------------------------------------------------------------
// Classifier with fused temporal layer-2
// ---------------------------------------------------------------------------
__global__ __launch_bounds__(256) void k_cls(const float* __restrict__ m,
                                             const float* __restrict__ g,
                                             const float* __restrict__ W2c,
                                             const float* __restrict__ cW1,
                                             const float* __restrict__ bc,
                                             const float* __restrict__ cW2,
                                             const float* __restrict__ cb2,
                                             float* __restrict__ out, int N) {
    __shared__ float Ws[128 * 64];
    int tid = threadIdx.x, lane = tid & 63;
    for (int i = tid; i < 128 * 64; i += 256) Ws[i] = (i < 4096) ? W2c[i] : cW1[i];
    __syncthreads();
    int n0 = blockIdx.x * 4 + (tid >> 6);
    int n  = __builtin_amdgcn_readfirstlane(n0 < N ? n0 : N - 1);

    const float* tp = m + (size_t)n * 64;
    const float* gp = g + (size_t)n * 64;
    float acc = bc[lane];
#pragma unroll
    for (int i0 = 0; i0 < 64; i0 += 8) {
        float xv[8];
#pragma unroll
        for (int k = 0; k < 8; ++k) xv[k] = tp[i0 + k];
#pragma unroll
        for (int k = 0; k < 8; ++k) acc = fmaf(xv[k], Ws[(i0 + k) * 64 + lane], acc);
    }
#pragma unroll
    for (int i0 = 0; i0 < 64; i0 += 8) {
        float xv[8];
#pragma unroll
        for (int k = 0; k < 8; ++k) xv[k] = gp[i0 + k];
#pragma unroll
        for (int k = 0; k < 8; ++k) acc = fmaf(xv[k], Ws[(64 + i0 + k) * 64 + lane], acc);
    }
    acc = fmaxf(acc, 0.f);
    float p = acc * cW2[lane];
#pragma unroll
    for (int msk = 1; msk < 64; msk <<= 1) p += __shfl_xor(p, msk);
    if (n0 < N && lane == 0) out[n] = 1.f / (1.f + __expf(-(p + cb2[0])));
}

// ---------------------------------------------------------------------------
extern "C" void kernel_launch(void* const* d_in, const int* in_sizes, int n_in,
                              void* d_out, int out_size, void* d_ws, size_t ws_size,
                              hipStream_t stream) {
    const float* td   = (const float*)d_in[0];
    const float* x    = (const float*)d_in[1];
    const int*   ei   = (const int*)d_in[2];
    const float* tW1  = (const float*)d_in[3];
    const float* tb1  = (const float*)d_in[4];
    const float* tW2  = (const float*)d_in[5];
    const float* tb2  = (const float*)d_in[6];
    const float* gW1  = (const float*)d_in[7];
    const float* ga1s = (const float*)d_in[8];
    const float* ga1d = (const float*)d_in[9];
    const float* gb1  = (const float*)d_in[10];
    const float* gW2  = (const float*)d_in[11];
    const float* ga2s = (const float*)d_in[12];
    const float* ga2d = (const float*)d_in[13];
    const float* gb2  = (const float*)d_in[14];
    const float* cW1  = (const float*)d_in[15];
    const float* cb1  = (const float*)d_in[16];
    const float* cW2  = (const float*)d_in[17];
    const float* cb2  = (const float*)d_in[18];

    int N = in_sizes[1] / 10;
    int E = in_sizes[2] / 2;

    float* fws   = (float*)d_ws;
    float* mbuf  = fws;                                        // [N,64] fp32
    unsigned short* h1b = (unsigned short*)(fws + (size_t)N * 64);  // [N,128] bf16
    float* out1  = fws + (size_t)N * 128;                      // [N,128] fp32
    float* a1s   = fws + (size_t)N * 256;
    float* a1d   = fws + (size_t)N * 260;
    unsigned short* h2b = h1b;      // reuse (h1 dead after k_g1b)
    float* a2s   = a1s;             // reuse
    float* a2d   = a1d;             // reuse
    float* gbuf  = out1;            // reuse (out1 dead after k_g2a)

    int* ib       = (int*)(fws + (size_t)N * 264);
    int* counts   = ib;
    int* rowptr   = ib + N;
    int* nxt      = ib + 2 * N + 1;
    int* partials = ib + 3 * N + 1;
    int* col      = ib + 3 * N + 1 + 128;

    float* W2c = (float*)nxt;       // overlay (dead after k_scatter)
    float* bcf = W2c + 4096;

    hipMemsetAsync(counts, 0, (size_t)N * sizeof(int), stream);

    int NB = (N + 1023) / 1024;
    k_count  <<<(E + 255) / 256, 256, 0, stream>>>(ei, counts, E);
    k_scan1  <<<NB, 1024, 0, stream>>>(counts, rowptr, partials, N);
    k_scan2  <<<1, 64, 0, stream>>>(partials, NB);
    k_scan3  <<<(N + 1 + 255) / 256, 256, 0, stream>>>(rowptr, partials, nxt, N);
    k_scatter<<<(E + 255) / 256, 256, 0, stream>>>(ei, nxt, col, E);
    k_fuse   <<<17, 256, 0, stream>>>(tW2, cW1, tb2, cb1, W2c, bcf);

    int nb4 = (N + 3) / 4;
    k_temporal<<<2048, 256, 0, stream>>>(td, tW1, tb1, mbuf, N);
    k_g1a     <<<nb4, 256, 0, stream>>>(x, gW1, ga1s, ga1d, h1b, a1s, a1d, N);
    k_g1b     <<<nb4, 256, 0, stream>>>(rowptr, col, (const unsigned int*)h1b, a1s, a1d, gb1, out1, N);
    k_g2a     <<<nb4, 256, 0, stream>>>(out1, gW2, ga2s, ga2d, h2b, a2s, a2d, N);
    k_g2b     <<<nb4, 256, 0, stream>>>(rowptr, col, (const unsigned int*)h2b, a2s, a2d, gb2, gbuf, N);
    k_cls     <<<nb4, 256, 0, stream>>>(mbuf, gbuf, W2c, cW1, bcf, cW2, cb2, (float*)d_out, N);
}

// Round 5
// 664.067 us; speedup vs baseline: 1.3892x; 1.0778x over previous
//
#include <hip/hip_runtime.h>
#include <hip/hip_bf16.h>

#define DEV_INLINE __device__ __forceinline__

typedef __attribute__((ext_vector_type(8))) short short8v;
typedef __attribute__((ext_vector_type(4))) float f32x4;

DEV_INLINE float lrelu(float v) { return fmaxf(v, 0.2f * v); }

DEV_INLINE unsigned int cvt_pk_bf16(float lo, float hi) {
    unsigned int r;
    asm("v_cvt_pk_bf16_f32 %0, %1, %2" : "=v"(r) : "v"(lo), "v"(hi));
    return r;
}

DEV_INLINE unsigned short f2bf_rne(float f) {
    unsigned int b = __float_as_uint(f);
    return (unsigned short)((b + 0x7FFFu + ((b >> 16) & 1u)) >> 16);
}

DEV_INLINE float bf_lo(unsigned int u) { return __uint_as_float(u << 16); }
DEV_INLINE float bf_hi(unsigned int u) { return __uint_as_float(u & 0xFFFF0000u); }

// ---------------------------------------------------------------------------
// CSR build kernels
// ---------------------------------------------------------------------------
__global__ void k_count(const int* __restrict__ ei, int* __restrict__ counts, int E) {
    int e = blockIdx.x * blockDim.x + threadIdx.x;
    if (e < E) atomicAdd(&counts[ei[E + e]], 1);
}

__global__ __launch_bounds__(1024) void k_scan1(const int* __restrict__ counts,
                                                int* __restrict__ rowptr,
                                                int* __restrict__ partials, int N) {
    __shared__ int sd[1024];
    int li = threadIdx.x;
    int i  = blockIdx.x * 1024 + li;
    int v  = (i < N) ? counts[i] : 0;
    sd[li] = v;
    __syncthreads();
    for (int off = 1; off < 1024; off <<= 1) {
        int t = (li >= off) ? sd[li - off] : 0;
        __syncthreads();
        sd[li] += t;
        __syncthreads();
    }
    int inc = sd[li];
    if (i < N) rowptr[i + 1] = inc;
    if (li == 1023) partials[blockIdx.x] = inc;   // raw chunk totals
}

// scan3 with inlined cross-chunk prefix (partials are raw totals; <=97 adds)
__global__ void k_scan3(int* __restrict__ rowptr, const int* __restrict__ partials,
                        int* __restrict__ nxt, int N) {
    int i = blockIdx.x * blockDim.x + threadIdx.x;
    if (i > N) return;
    int v;
    if (i == 0) { v = 0; rowptr[0] = 0; }
    else {
        int blk = (i - 1) >> 10;
        int pp = 0;
        for (int b = 0; b < blk; ++b) pp += partials[b];
        v = rowptr[i] + pp;
        rowptr[i] = v;
    }
    if (i < N) nxt[i] = v;
}

// Multi-pass scatter: register-cache 8 edges/thread, 16 dst-range passes so
// col writes within a pass land in a 400KB window (lines fill before evict).
#define SC_K 8
#define SC_P 16
__global__ __launch_bounds__(256) void k_scatter(const int* __restrict__ ei,
                                                 int* __restrict__ nxt,
                                                 int* __restrict__ col,
                                                 int E, int range) {
    int t = threadIdx.x;
    int base = blockIdx.x * (256 * SC_K);
    int s[SC_K], d[SC_K];
#pragma unroll
    for (int k = 0; k < SC_K; ++k) {
        int e = base + k * 256 + t;
        bool v = (e < E);
        s[k] = v ? ei[e] : 0;
        d[k] = v ? ei[E + e] : -1;       // -1 never matches any range
    }
    int lo = 0;
    for (int p = 0; p < SC_P; ++p, lo += range) {
        int hi = lo + range;
#pragma unroll
        for (int k = 0; k < SC_K; ++k) {
            if (d[k] >= lo && d[k] < hi) {
                int pos = atomicAdd(&nxt[d[k]], 1);
                col[pos] = s[k];
            }
        }
        __syncthreads();                 // keep block's lanes pass-aligned
    }
}

// ---------------------------------------------------------------------------
// Fold temporal layer-2 into classifier:  W2c = tW2 @ cW1[0:64,:],
// bc = tb2 @ cW1[0:64,:] + cb1   (mean/linear commute, exact)
// ---------------------------------------------------------------------------
__global__ void k_fuse(const float* __restrict__ tW2, const float* __restrict__ cW1,
                       const float* __restrict__ tb2, const float* __restrict__ cb1,
                       float* __restrict__ W2c, float* __restrict__ bc) {
    int gid = blockIdx.x * 256 + threadIdx.x;
    if (gid < 4096) {
        int i = gid >> 6, c = gid & 63;
        float s = 0.f;
#pragma unroll 8
        for (int k = 0; k < 64; ++k) s = fmaf(tW2[i * 64 + k], cW1[k * 64 + c], s);
        W2c[gid] = s;
    } else if (gid < 4160) {
        int c = gid - 4096;
        float s = cb1[c];
#pragma unroll 8
        for (int k = 0; k < 64; ++k) s = fmaf(tb2[k], cW1[k * 64 + c], s);
        bc[c] = s;
    }
}

// ---------------------------------------------------------------------------
// Temporal encoder layer-1 + mean over T, via MFMA 16x16x32 bf16.
// ---------------------------------------------------------------------------
__global__ __launch_bounds__(256) void k_temporal(const float* __restrict__ td,
                                                  const float* __restrict__ tW1,
                                                  const float* __restrict__ tb1,
                                                  float* __restrict__ mbuf, int N) {
    int lane = threadIdx.x & 63;
    int wid  = (blockIdx.x * blockDim.x + threadIdx.x) >> 6;
    int nwav = (gridDim.x * blockDim.x) >> 6;
    int col  = lane & 15;
    int g    = lane >> 4;

    short8v B[4];
#pragma unroll
    for (int cb = 0; cb < 4; ++cb) {
        union { short8v v; unsigned short u[8]; } bu;
#pragma unroll
        for (int j = 0; j < 8; ++j) {
            int f = g * 8 + j;
            int c = cb * 16 + col;
            float w = (f < 10) ? tW1[f * 64 + c] : ((f == 10) ? tb1[c] : 0.f);
            bu.u[j] = f2bf_rne(w);
        }
        B[cb] = bu.v;
    }

    for (int n = wid; n < N; n += nwav) {
        const float* base = td + (size_t)n * 500;
        float sum0 = 0.f, sum1 = 0.f, sum2 = 0.f, sum3 = 0.f;
#pragma unroll
        for (int tt = 0; tt < 4; ++tt) {
            int t = tt * 16 + col;
            float x0 = 0.f, x1 = 0.f, x2 = 0.f, x3 = 0.f;
            float x4 = 0.f, x5 = 0.f, x6 = 0.f, x7 = 0.f;
            bool valid = (t < 50);
            const float* rp = base + t * 10;
            if (g == 0 && valid) {
                float2 p0 = *reinterpret_cast<const float2*>(rp);
                float2 p1 = *reinterpret_cast<const float2*>(rp + 2);
                float2 p2 = *reinterpret_cast<const float2*>(rp + 4);
                float2 p3 = *reinterpret_cast<const float2*>(rp + 6);
                x0 = p0.x; x1 = p0.y; x2 = p1.x; x3 = p1.y;
                x4 = p2.x; x5 = p2.y; x6 = p3.x; x7 = p3.y;
            } else if (g == 1 && valid) {
                float2 p4 = *reinterpret_cast<const float2*>(rp + 8);
                x0 = p4.x; x1 = p4.y; x2 = 1.0f;
            }
            union { short8v v; unsigned int w[4]; } au;
            au.w[0] = cvt_pk_bf16(x0, x1);
            au.w[1] = cvt_pk_bf16(x2, x3);
            au.w[2] = cvt_pk_bf16(x4, x5);
            au.w[3] = cvt_pk_bf16(x6, x7);

            f32x4 z = {0.f, 0.f, 0.f, 0.f};
            f32x4 c0 = __builtin_amdgcn_mfma_f32_16x16x32_bf16(au.v, B[0], z, 0, 0, 0);
            f32x4 c1 = __builtin_amdgcn_mfma_f32_16x16x32_bf16(au.v, B[1], z, 0, 0, 0);
            f32x4 c2 = __builtin_amdgcn_mfma_f32_16x16x32_bf16(au.v, B[2], z, 0, 0, 0);
            f32x4 c3 = __builtin_amdgcn_mfma_f32_16x16x32_bf16(au.v, B[3], z, 0, 0, 0);
#pragma unroll
            for (int i = 0; i < 4; ++i) {
                sum0 += fmaxf(c0[i], 0.f);
                sum1 += fmaxf(c1[i], 0.f);
                sum2 += fmaxf(c2[i], 0.f);
                sum3 += fmaxf(c3[i], 0.f);
            }
        }
        sum0 += __shfl_xor(sum0, 16); sum0 += __shfl_xor(sum0, 32);
        sum1 += __shfl_xor(sum1, 16); sum1 += __shfl_xor(sum1, 32);
        sum2 += __shfl_xor(sum2, 16); sum2 += __shfl_xor(sum2, 32);
        sum3 += __shfl_xor(sum3, 16); sum3 += __shfl_xor(sum3, 32);
        float v = (g == 0) ? sum0 : (g == 1) ? sum1 : (g == 2) ? sum2 : sum3;
        mbuf[(size_t)n * 64 + lane] = v * 0.02f;
    }
}

// ---------------------------------------------------------------------------
// GATConv1 projection + attention scores. h1b bf16 [n,128], a1s/a1d fp32 [n,4]
// ---------------------------------------------------------------------------
__global__ __launch_bounds__(256) void k_g1a(const float* __restrict__ x,
                                             const float* __restrict__ gW1,
                                             const float* __restrict__ as_w,
                                             const float* __restrict__ ad_w,
                                             unsigned short* __restrict__ h1b,
                                             float* __restrict__ a1s,
                                             float* __restrict__ a1d, int N) {
    int tid = threadIdx.x, lane = tid & 63;
    int n0 = blockIdx.x * 4 + (tid >> 6);
    int n  = __builtin_amdgcn_readfirstlane(n0 < N ? n0 : N - 1);

    float wa[10], wb[10];
#pragma unroll
    for (int i = 0; i < 10; ++i) { wa[i] = gW1[i * 128 + lane]; wb[i] = gW1[i * 128 + 64 + lane]; }
    const float* xp = x + (size_t)n * 10;
    float ha = 0.f, hb = 0.f;
#pragma unroll
    for (int i = 0; i < 10; ++i) { float xv = xp[i]; ha = fmaf(xv, wa[i], ha); hb = fmaf(xv, wb[i], hb); }

    int c = lane & 31;
    int headA = lane >> 5;
    float ps_a = ha * as_w[headA * 32 + c];
    float ps_b = hb * as_w[(headA + 2) * 32 + c];
    float pd_a = ha * ad_w[headA * 32 + c];
    float pd_b = hb * ad_w[(headA + 2) * 32 + c];
#pragma unroll
    for (int m = 1; m < 32; m <<= 1) {
        ps_a += __shfl_xor(ps_a, m); ps_b += __shfl_xor(ps_b, m);
        pd_a += __shfl_xor(pd_a, m); pd_b += __shfl_xor(pd_b, m);
    }
    if (n0 < N) {
        h1b[(size_t)n * 128 + lane]      = f2bf_rne(ha);
        h1b[(size_t)n * 128 + 64 + lane] = f2bf_rne(hb);
        if (c == 0) {
            a1s[n * 4 + headA]     = ps_a;
            a1s[n * 4 + 2 + headA] = ps_b;
            a1d[n * 4 + headA]     = pd_a;
            a1d[n * 4 + 2 + headA] = pd_b;
        }
    }
}

// ---------------------------------------------------------------------------
// GATConv1 aggregation + bias + ELU. Lane l owns channels (2l,2l+1), head l>>4.
// ---------------------------------------------------------------------------
__global__ __launch_bounds__(256) void k_g1b(const int* __restrict__ rowptr,
                                             const int* __restrict__ col,
                                             const unsigned int* __restrict__ h1u,
                                             const float* __restrict__ a1s,
                                             const float* __restrict__ a1d,
                                             const float* __restrict__ gb1,
                                             float* __restrict__ out1, int N) {
    int tid = threadIdx.x, lane = tid & 63;
    int n0 = blockIdx.x * 4 + (tid >> 6);
    int n  = __builtin_amdgcn_readfirstlane(n0 < N ? n0 : N - 1);

    int start = rowptr[n], end = rowptr[n + 1];
    int hsel = lane >> 4;
    float advh = a1d[n * 4 + hsel];
    float gbl  = gb1[2 * lane];
    float gbh  = gb1[2 * lane + 1];

    float w  = __expf(lrelu(a1s[n * 4 + hsel] + advh));
    float den = w;
    unsigned int u = h1u[(size_t)n * 64 + lane];
    float accL = w * bf_lo(u), accH = w * bf_hi(u);

    int e = start;
    for (; e + 2 <= end; e += 2) {
        int s0 = col[e], s1 = col[e + 1];
        float q0 = a1s[s0 * 4 + hsel];
        float q1 = a1s[s1 * 4 + hsel];
        unsigned int u0 = h1u[(size_t)s0 * 64 + lane];
        unsigned int u1 = h1u[(size_t)s1 * 64 + lane];
        float w0 = __expf(lrelu(q0 + advh));
        float w1 = __expf(lrelu(q1 + advh));
        den += w0 + w1;
        accL = fmaf(w0, bf_lo(u0), accL);
        accH = fmaf(w0, bf_hi(u0), accH);
        accL = fmaf(w1, bf_lo(u1), accL);
        accH = fmaf(w1, bf_hi(u1), accH);
    }
    if (e < end) {
        int s = col[e];
        float q = a1s[s * 4 + hsel];
        unsigned int us = h1u[(size_t)s * 64 + lane];
        float ws = __expf(lrelu(q + advh));
        den += ws;
        accL = fmaf(ws, bf_lo(us), accL);
        accH = fmaf(ws, bf_hi(us), accH);
    }

    float inv = 1.f / den;
    float vL = accL * inv + gbl;
    float vH = accH * inv + gbh;
    vL = (vL > 0.f) ? vL : (__expf(vL) - 1.f);   // ELU
    vH = (vH > 0.f) ? vH : (__expf(vH) - 1.f);
    if (n0 < N)
        *reinterpret_cast<float2*>(out1 + (size_t)n * 128 + 2 * lane) = make_float2(vL, vH);
}

// ---------------------------------------------------------------------------
// GATConv2 projection (128->64) + attention scores; h2 stored packed bf16
// ---------------------------------------------------------------------------
__global__ __launch_bounds__(256) void k_g2a(const float* __restrict__ out1,
                                             const float* __restrict__ gW2,
                                             const float* __restrict__ a2sw,
                                             const float* __restrict__ a2dw,
                                             unsigned short* __restrict__ h2b,
                                             float* __restrict__ a2s,
                                             float* __restrict__ a2d, int N) {
    __shared__ float Ws[128 * 64];
    int tid = threadIdx.x, lane = tid & 63;
    for (int i = tid; i < 128 * 64; i += 256) Ws[i] = gW2[i];
    __syncthreads();
    int n0 = blockIdx.x * 4 + (tid >> 6);
    int n  = __builtin_amdgcn_readfirstlane(n0 < N ? n0 : N - 1);

    const float* xr = out1 + (size_t)n * 128;
    float acc = 0.f;
#pragma unroll
    for (int i0 = 0; i0 < 128; i0 += 8) {
        float xv[8];
#pragma unroll
        for (int k = 0; k < 8; ++k) xv[k] = xr[i0 + k];
#pragma unroll
        for (int k = 0; k < 8; ++k) acc = fmaf(xv[k], Ws[(i0 + k) * 64 + lane], acc);
    }
    float ps = acc * a2sw[lane], pd = acc * a2dw[lane];
#pragma unroll
    for (int msk = 1; msk < 64; msk <<= 1) { ps += __shfl_xor(ps, msk); pd += __shfl_xor(pd, msk); }
    if (n0 < N) {
        h2b[(size_t)n * 64 + lane] = f2bf_rne(acc);
        if (lane == 0) { a2s[n] = ps; a2d[n] = pd; }
    }
}

// ---------------------------------------------------------------------------
// GATConv2 aggregation + bias. Half-wave per edge, packed bf16 channels.
// ---------------------------------------------------------------------------
__global__ __launch_bounds__(256) void k_g2b(const int* __restrict__ rowptr,
                                             const int* __restrict__ col,
                                             const unsigned int* __restrict__ h2u,
                                             const float* __restrict__ a2s,
                                             const float* __restrict__ a2d,
                                             const float* __restrict__ gb2,
                                             float* __restrict__ g, int N) {
    int tid = threadIdx.x, lane = tid & 63;
    int n0 = blockIdx.x * 4 + (tid >> 6);
    int n  = __builtin_amdgcn_readfirstlane(n0 < N ? n0 : N - 1);

    int start = rowptr[n], end = rowptr[n + 1];
    int h = lane >> 5, c = lane & 31;
    float ad = a2d[n];

    float den = 0.f, accL = 0.f, accH = 0.f;
    if (h == 0) {
        float w = __expf(lrelu(a2s[n] + ad));
        unsigned int u = h2u[(size_t)n * 32 + c];
        den = w; accL = w * bf_lo(u); accH = w * bf_hi(u);
    }
    for (int e = start + h; e < end; e += 2) {
        int s = col[e];
        float w = __expf(lrelu(a2s[s] + ad));
        unsigned int u = h2u[(size_t)s * 32 + c];
        den += w;
        accL = fmaf(w, bf_lo(u), accL);
        accH = fmaf(w, bf_hi(u), accH);
    }
    den  += __shfl_xor(den, 32);
    accL += __shfl_xor(accL, 32);
    accH += __shfl_xor(accH, 32);

    if (n0 < N && h == 0) {
        float inv = 1.f / den;
        *reinterpret_cast<float2*>(g + (size_t)n * 64 + 2 * c) =
            make_float2(accL * inv + gb2[2 * c], accH * inv + gb2[2 * c + 1]);
    }
}

// ---------------------------------------------------------------------------
// Classifier with fused temporal layer-2
// ---------------------------------------------------------------------------
__global__ __launch_bounds__(256) void k_cls(const float* __restrict__ m,
                                             const float* __restrict__ g,
                                             const float* __restrict__ W2c,
                                             const float* __restrict__ cW1,
                                             const float* __restrict__ bc,
                                             const float* __restrict__ cW2,
                                             const float* __restrict__ cb2,
                                             float* __restrict__ out, int N) {
    __shared__ float Ws[128 * 64];
    int tid = threadIdx.x, lane = tid & 63;
    for (int i = tid; i < 128 * 64; i += 256) Ws[i] = (i < 4096) ? W2c[i] : cW1[i];
    __syncthreads();
    int n0 = blockIdx.x * 4 + (tid >> 6);
    int n  = __builtin_amdgcn_readfirstlane(n0 < N ? n0 : N - 1);

    const float* tp = m + (size_t)n * 64;
    const float* gp = g + (size_t)n * 64;
    float acc = bc[lane];
#pragma unroll
    for (int i0 = 0; i0 < 64; i0 += 8) {
        float xv[8];
#pragma unroll
        for (int k = 0; k < 8; ++k) xv[k] = tp[i0 + k];
#pragma unroll
        for (int k = 0; k < 8; ++k) acc = fmaf(xv[k], Ws[(i0 + k) * 64 + lane], acc);
    }
#pragma unroll
    for (int i0 = 0; i0 < 64; i0 += 8) {
        float xv[8];
#pragma unroll
        for (int k = 0; k < 8; ++k) xv[k] = gp[i0 + k];
#pragma unroll
        for (int k = 0; k < 8; ++k) acc = fmaf(xv[k], Ws[(64 + i0 + k) * 64 + lane], acc);
    }
    acc = fmaxf(acc, 0.f);
    float p = acc * cW2[lane];
#pragma unroll
    for (int msk = 1; msk < 64; msk <<= 1) p += __shfl_xor(p, msk);
    if (n0 < N && lane == 0) out[n] = 1.f / (1.f + __expf(-(p + cb2[0])));
}

// ---------------------------------------------------------------------------
extern "C" void kernel_launch(void* const* d_in, const int* in_sizes, int n_in,
                              void* d_out, int out_size, void* d_ws, size_t ws_size,
                              hipStream_t stream) {
    const float* td   = (const float*)d_in[0];
    const float* x    = (const float*)d_in[1];
    const int*   ei   = (const int*)d_in[2];
    const float* tW1  = (const float*)d_in[3];
    const float* tb1  = (const float*)d_in[4];
    const float* tW2  = (const float*)d_in[5];
    const float* tb2  = (const float*)d_in[6];
    const float* gW1  = (const float*)d_in[7];
    const float* ga1s = (const float*)d_in[8];
    const float* ga1d = (const float*)d_in[9];
    const float* gb1  = (const float*)d_in[10];
    const float* gW2  = (const float*)d_in[11];
    const float* ga2s = (const float*)d_in[12];
    const float* ga2d = (const float*)d_in[13];
    const float* gb2  = (const float*)d_in[14];
    const float* cW1  = (const float*)d_in[15];
    const float* cb1  = (const float*)d_in[16];
    const float* cW2  = (const float*)d_in[17];
    const float* cb2  = (const float*)d_in[18];

    int N = in_sizes[1] / 10;
    int E = in_sizes[2] / 2;

    float* fws   = (float*)d_ws;
    float* mbuf  = fws;                                        // [N,64] fp32
    unsigned short* h1b = (unsigned short*)(fws + (size_t)N * 64);  // [N,128] bf16
    float* out1  = fws + (size_t)N * 128;                      // [N,128] fp32
    float* a1s   = fws + (size_t)N * 256;
    float* a1d   = fws + (size_t)N * 260;
    unsigned short* h2b = h1b;      // reuse (h1 dead after k_g1b)
    float* a2s   = a1s;             // reuse
    float* a2d   = a1d;             // reuse
    float* gbuf  = out1;            // reuse (out1 dead after k_g2a)

    int* ib       = (int*)(fws + (size_t)N * 264);
    int* counts   = ib;
    int* rowptr   = ib + N;
    int* nxt      = ib + 2 * N + 1;
    int* partials = ib + 3 * N + 1;
    int* col      = ib + 3 * N + 1 + 128;

    float* W2c = (float*)nxt;       // overlay (dead after k_scatter)
    float* bcf = W2c + 4096;

    hipMemsetAsync(counts, 0, (size_t)N * sizeof(int), stream);

    int NB = (N + 1023) / 1024;
    int range = (N + SC_P - 1) / SC_P;
    k_count  <<<(E + 255) / 256, 256, 0, stream>>>(ei, counts, E);
    k_scan1  <<<NB, 1024, 0, stream>>>(counts, rowptr, partials, N);
    k_scan3  <<<(N + 1 + 255) / 256, 256, 0, stream>>>(rowptr, partials, nxt, N);
    k_scatter<<<(E + 256 * SC_K - 1) / (256 * SC_K), 256, 0, stream>>>(ei, nxt, col, E, range);
    k_fuse   <<<17, 256, 0, stream>>>(tW2, cW1, tb2, cb1, W2c, bcf);

    int nb4 = (N + 3) / 4;
    k_temporal<<<2048, 256, 0, stream>>>(td, tW1, tb1, mbuf, N);
    k_g1a     <<<nb4, 256, 0, stream>>>(x, gW1, ga1s, ga1d, h1b, a1s, a1d, N);
    k_g1b     <<<nb4, 256, 0, stream>>>(rowptr, col, (const unsigned int*)h1b, a1s, a1d, gb1, out1, N);
    k_g2a     <<<nb4, 256, 0, stream>>>(out1, gW2, ga2s, ga2d, h2b, a2s, a2d, N);
    k_g2b     <<<nb4, 256, 0, stream>>>(rowptr, col, (const unsigned int*)h2b, a2s, a2d, gb2, gbuf, N);
    k_cls     <<<nb4, 256, 0, stream>>>(mbuf, gbuf, W2c, cW1, bcf, cW2, cb2, (float*)d_out, N);
}

// Round 6
// 482.209 us; speedup vs baseline: 1.9132x; 1.3771x over previous
//
#include <hip/hip_runtime.h>
#include <hip/hip_bf16.h>

#define DEV_INLINE __device__ __forceinline__

typedef __attribute__((ext_vector_type(8))) short short8v;
typedef __attribute__((ext_vector_type(4))) float f32x4;

DEV_INLINE float lrelu(float v) { return fmaxf(v, 0.2f * v); }

DEV_INLINE unsigned int cvt_pk_bf16(float lo, float hi) {
    unsigned int r;
    asm("v_cvt_pk_bf16_f32 %0, %1, %2" : "=v"(r) : "v"(lo), "v"(hi));
    return r;
}

DEV_INLINE unsigned short f2bf_rne(float f) {
    unsigned int b = __float_as_uint(f);
    return (unsigned short)((b + 0x7FFFu + ((b >> 16) & 1u)) >> 16);
}

DEV_INLINE unsigned int pack_bf16(float lo, float hi) {
    return (unsigned int)f2bf_rne(lo) | ((unsigned int)f2bf_rne(hi) << 16);
}

DEV_INLINE float bf_lo(unsigned int u) { return __uint_as_float(u << 16); }
DEV_INLINE float bf_hi(unsigned int u) { return __uint_as_float(u & 0xFFFF0000u); }

// ---------------------------------------------------------------------------
// CSR build kernels
// ---------------------------------------------------------------------------
__global__ void k_count(const int* __restrict__ ei, int* __restrict__ counts, int E) {
    int e = blockIdx.x * blockDim.x + threadIdx.x;
    if (e < E) atomicAdd(&counts[ei[E + e]], 1);
}

__global__ __launch_bounds__(1024) void k_scan1(const int* __restrict__ counts,
                                                int* __restrict__ rowptr,
                                                int* __restrict__ partials, int N) {
    __shared__ int sd[1024];
    int li = threadIdx.x;
    int i  = blockIdx.x * 1024 + li;
    int v  = (i < N) ? counts[i] : 0;
    sd[li] = v;
    __syncthreads();
    for (int off = 1; off < 1024; off <<= 1) {
        int t = (li >= off) ? sd[li - off] : 0;
        __syncthreads();
        sd[li] += t;
        __syncthreads();
    }
    int inc = sd[li];
    if (i < N) rowptr[i + 1] = inc;
    if (li == 1023) partials[blockIdx.x] = inc;   // raw chunk totals
}

__global__ void k_scan3(int* __restrict__ rowptr, const int* __restrict__ partials,
                        int* __restrict__ nxt, int N) {
    int i = blockIdx.x * blockDim.x + threadIdx.x;
    if (i > N) return;
    int v;
    if (i == 0) { v = 0; rowptr[0] = 0; }
    else {
        int blk = (i - 1) >> 10;
        int pp = 0;
        for (int b = 0; b < blk; ++b) pp += partials[b];
        v = rowptr[i] + pp;
        rowptr[i] = v;
    }
    if (i < N) nxt[i] = v;
}

#define SC_K 8
#define SC_P 16
__global__ __launch_bounds__(256) void k_scatter(const int* __restrict__ ei,
                                                 int* __restrict__ nxt,
                                                 int* __restrict__ col,
                                                 int E, int range) {
    int t = threadIdx.x;
    int base = blockIdx.x * (256 * SC_K);
    int s[SC_K], d[SC_K];
#pragma unroll
    for (int k = 0; k < SC_K; ++k) {
        int e = base + k * 256 + t;
        bool v = (e < E);
        s[k] = v ? ei[e] : 0;
        d[k] = v ? ei[E + e] : -1;
    }
    int lo = 0;
    for (int p = 0; p < SC_P; ++p, lo += range) {
        int hi = lo + range;
#pragma unroll
        for (int k = 0; k < SC_K; ++k) {
            if (d[k] >= lo && d[k] < hi) {
                int pos = atomicAdd(&nxt[d[k]], 1);
                col[pos] = s[k];
            }
        }
        __syncthreads();
    }
}

// ---------------------------------------------------------------------------
// Fused classifier weights, bf16:  Wf[0:64]  = tW2 @ cW1[0:64,:]
//                                  Wf[64:128]= cW1[64:128,:]
// bc = tb2 @ cW1[0:64,:] + cb1  (fp32)
// ---------------------------------------------------------------------------
__global__ void k_fuse(const float* __restrict__ tW2, const float* __restrict__ cW1,
                       const float* __restrict__ tb2, const float* __restrict__ cb1,
                       unsigned short* __restrict__ Wf, float* __restrict__ bc) {
    int gid = blockIdx.x * 256 + threadIdx.x;
    if (gid < 4096) {
        int i = gid >> 6, c = gid & 63;
        float s = 0.f;
#pragma unroll 8
        for (int k = 0; k < 64; ++k) s = fmaf(tW2[i * 64 + k], cW1[k * 64 + c], s);
        Wf[gid] = f2bf_rne(s);
    } else if (gid < 8192) {
        Wf[gid] = f2bf_rne(cW1[gid]);
    } else if (gid < 8256) {
        int c = gid - 8192;
        float s = cb1[c];
#pragma unroll 8
        for (int k = 0; k < 64; ++k) s = fmaf(tb2[k], cW1[k * 64 + c], s);
        bc[c] = s;
    }
}

// ---------------------------------------------------------------------------
// Temporal encoder layer-1 + mean over T, MFMA 16x16x32 bf16. Output bf16.
// ---------------------------------------------------------------------------
__global__ __launch_bounds__(256) void k_temporal(const float* __restrict__ td,
                                                  const float* __restrict__ tW1,
                                                  const float* __restrict__ tb1,
                                                  unsigned short* __restrict__ mb, int N) {
    int lane = threadIdx.x & 63;
    int wid  = (blockIdx.x * blockDim.x + threadIdx.x) >> 6;
    int nwav = (gridDim.x * blockDim.x) >> 6;
    int col  = lane & 15;
    int g    = lane >> 4;

    short8v B[4];
#pragma unroll
    for (int cb = 0; cb < 4; ++cb) {
        union { short8v v; unsigned short u[8]; } bu;
#pragma unroll
        for (int j = 0; j < 8; ++j) {
            int f = g * 8 + j;
            int c = cb * 16 + col;
            float w = (f < 10) ? tW1[f * 64 + c] : ((f == 10) ? tb1[c] : 0.f);
            bu.u[j] = f2bf_rne(w);
        }
        B[cb] = bu.v;
    }

    for (int n = wid; n < N; n += nwav) {
        const float* base = td + (size_t)n * 500;
        float sum0 = 0.f, sum1 = 0.f, sum2 = 0.f, sum3 = 0.f;
#pragma unroll
        for (int tt = 0; tt < 4; ++tt) {
            int t = tt * 16 + col;
            float x0 = 0.f, x1 = 0.f, x2 = 0.f, x3 = 0.f;
            float x4 = 0.f, x5 = 0.f, x6 = 0.f, x7 = 0.f;
            bool valid = (t < 50);
            const float* rp = base + t * 10;
            if (g == 0 && valid) {
                float2 p0 = *reinterpret_cast<const float2*>(rp);
                float2 p1 = *reinterpret_cast<const float2*>(rp + 2);
                float2 p2 = *reinterpret_cast<const float2*>(rp + 4);
                float2 p3 = *reinterpret_cast<const float2*>(rp + 6);
                x0 = p0.x; x1 = p0.y; x2 = p1.x; x3 = p1.y;
                x4 = p2.x; x5 = p2.y; x6 = p3.x; x7 = p3.y;
            } else if (g == 1 && valid) {
                float2 p4 = *reinterpret_cast<const float2*>(rp + 8);
                x0 = p4.x; x1 = p4.y; x2 = 1.0f;
            }
            union { short8v v; unsigned int w[4]; } au;
            au.w[0] = cvt_pk_bf16(x0, x1);
            au.w[1] = cvt_pk_bf16(x2, x3);
            au.w[2] = cvt_pk_bf16(x4, x5);
            au.w[3] = cvt_pk_bf16(x6, x7);

            f32x4 z = {0.f, 0.f, 0.f, 0.f};
            f32x4 c0 = __builtin_amdgcn_mfma_f32_16x16x32_bf16(au.v, B[0], z, 0, 0, 0);
            f32x4 c1 = __builtin_amdgcn_mfma_f32_16x16x32_bf16(au.v, B[1], z, 0, 0, 0);
            f32x4 c2 = __builtin_amdgcn_mfma_f32_16x16x32_bf16(au.v, B[2], z, 0, 0, 0);
            f32x4 c3 = __builtin_amdgcn_mfma_f32_16x16x32_bf16(au.v, B[3], z, 0, 0, 0);
#pragma unroll
            for (int i = 0; i < 4; ++i) {
                sum0 += fmaxf(c0[i], 0.f);
                sum1 += fmaxf(c1[i], 0.f);
                sum2 += fmaxf(c2[i], 0.f);
                sum3 += fmaxf(c3[i], 0.f);
            }
        }
        sum0 += __shfl_xor(sum0, 16); sum0 += __shfl_xor(sum0, 32);
        sum1 += __shfl_xor(sum1, 16); sum1 += __shfl_xor(sum1, 32);
        sum2 += __shfl_xor(sum2, 16); sum2 += __shfl_xor(sum2, 32);
        sum3 += __shfl_xor(sum3, 16); sum3 += __shfl_xor(sum3, 32);
        float v = (g == 0) ? sum0 : (g == 1) ? sum1 : (g == 2) ? sum2 : sum3;
        mb[(size_t)n * 64 + lane] = f2bf_rne(v * 0.02f);
    }
}

// ---------------------------------------------------------------------------
// GATConv1 projection + attention scores. h1b bf16 [n,128], a1s/a1d fp32 [n,4]
// ---------------------------------------------------------------------------
__global__ __launch_bounds__(256) void k_g1a(const float* __restrict__ x,
                                             const float* __restrict__ gW1,
                                             const float* __restrict__ as_w,
                                             const float* __restrict__ ad_w,
                                             unsigned short* __restrict__ h1b,
                                             float* __restrict__ a1s,
                                             float* __restrict__ a1d, int N) {
    int tid = threadIdx.x, lane = tid & 63;
    int n0 = blockIdx.x * 4 + (tid >> 6);
    int n  = __builtin_amdgcn_readfirstlane(n0 < N ? n0 : N - 1);

    float wa[10], wb[10];
#pragma unroll
    for (int i = 0; i < 10; ++i) { wa[i] = gW1[i * 128 + lane]; wb[i] = gW1[i * 128 + 64 + lane]; }
    const float* xp = x + (size_t)n * 10;
    float ha = 0.f, hb = 0.f;
#pragma unroll
    for (int i = 0; i < 10; ++i) { float xv = xp[i]; ha = fmaf(xv, wa[i], ha); hb = fmaf(xv, wb[i], hb); }

    int c = lane & 31;
    int headA = lane >> 5;
    float ps_a = ha * as_w[headA * 32 + c];
    float ps_b = hb * as_w[(headA + 2) * 32 + c];
    float pd_a = ha * ad_w[headA * 32 + c];
    float pd_b = hb * ad_w[(headA + 2) * 32 + c];
#pragma unroll
    for (int m = 1; m < 32; m <<= 1) {
        ps_a += __shfl_xor(ps_a, m); ps_b += __shfl_xor(ps_b, m);
        pd_a += __shfl_xor(pd_a, m); pd_b += __shfl_xor(pd_b, m);
    }
    if (n0 < N) {
        h1b[(size_t)n * 128 + lane]      = f2bf_rne(ha);
        h1b[(size_t)n * 128 + 64 + lane] = f2bf_rne(hb);
        if (c == 0) {
            a1s[n * 4 + headA]     = ps_a;
            a1s[n * 4 + 2 + headA] = ps_b;
            a1d[n * 4 + headA]     = pd_a;
            a1d[n * 4 + 2 + headA] = pd_b;
        }
    }
}

// ---------------------------------------------------------------------------
// GATConv1 aggregation + bias + ELU. Lane l owns channels (2l,2l+1), head l>>4.
// Output bf16-packed out1b [n,128].
// ---------------------------------------------------------------------------
__global__ __launch_bounds__(256) void k_g1b(const int* __restrict__ rowptr,
                                             const int* __restrict__ col,
                                             const unsigned int* __restrict__ h1u,
                                             const float* __restrict__ a1s,
                                             const float* __restrict__ a1d,
                                             const float* __restrict__ gb1,
                                             unsigned int* __restrict__ out1u, int N) {
    int tid = threadIdx.x, lane = tid & 63;
    int n0 = blockIdx.x * 4 + (tid >> 6);
    int n  = __builtin_amdgcn_readfirstlane(n0 < N ? n0 : N - 1);

    int start = rowptr[n], end = rowptr[n + 1];
    int hsel = lane >> 4;
    float advh = a1d[n * 4 + hsel];
    float gbl  = gb1[2 * lane];
    float gbh  = gb1[2 * lane + 1];

    float w  = __expf(lrelu(a1s[n * 4 + hsel] + advh));
    float den = w;
    unsigned int u = h1u[(size_t)n * 64 + lane];
    float accL = w * bf_lo(u), accH = w * bf_hi(u);

    int e = start;
    for (; e + 2 <= end; e += 2) {
        int s0 = col[e], s1 = col[e + 1];
        float q0 = a1s[s0 * 4 + hsel];
        float q1 = a1s[s1 * 4 + hsel];
        unsigned int u0 = h1u[(size_t)s0 * 64 + lane];
        unsigned int u1 = h1u[(size_t)s1 * 64 + lane];
        float w0 = __expf(lrelu(q0 + advh));
        float w1 = __expf(lrelu(q1 + advh));
        den += w0 + w1;
        accL = fmaf(w0, bf_lo(u0), accL);
        accH = fmaf(w0, bf_hi(u0), accH);
        accL = fmaf(w1, bf_lo(u1), accL);
        accH = fmaf(w1, bf_hi(u1), accH);
    }
    if (e < end) {
        int s = col[e];
        float q = a1s[s * 4 + hsel];
        unsigned int us = h1u[(size_t)s * 64 + lane];
        float ws = __expf(lrelu(q + advh));
        den += ws;
        accL = fmaf(ws, bf_lo(us), accL);
        accH = fmaf(ws, bf_hi(us), accH);
    }

    float inv = 1.f / den;
    float vL = accL * inv + gbl;
    float vH = accH * inv + gbh;
    vL = (vL > 0.f) ? vL : (__expf(vL) - 1.f);   // ELU
    vH = (vH > 0.f) ? vH : (__expf(vH) - 1.f);
    if (n0 < N) out1u[(size_t)n * 64 + lane] = pack_bf16(vL, vH);
}

// ---------------------------------------------------------------------------
// GATConv2 projection via MFMA: h2 = out1 @ gW2 (bf16 in/out), plus attention
// scores a2s/a2d. Wave = 16-node tile; B (gW2) register-resident.
// ---------------------------------------------------------------------------
__global__ __launch_bounds__(256) void k_g2a(const unsigned short* __restrict__ out1b,
                                             const float* __restrict__ gW2,
                                             const float* __restrict__ a2sw,
                                             const float* __restrict__ a2dw,
                                             unsigned short* __restrict__ h2b,
                                             float* __restrict__ a2s,
                                             float* __restrict__ a2d, int N) {
    int lane = threadIdx.x & 63;
    int wid  = (blockIdx.x * blockDim.x + threadIdx.x) >> 6;
    int nwav = (gridDim.x * blockDim.x) >> 6;
    int col = lane & 15, g4 = lane >> 4;

    short8v Bf[4][4];
#pragma unroll
    for (int ks = 0; ks < 4; ++ks)
#pragma unroll
        for (int cb = 0; cb < 4; ++cb) {
            union { short8v v; unsigned short u[8]; } bu;
#pragma unroll
            for (int j = 0; j < 8; ++j)
                bu.u[j] = f2bf_rne(gW2[(ks * 32 + g4 * 8 + j) * 64 + cb * 16 + col]);
            Bf[ks][cb] = bu.v;
        }
    float asv[4], adv[4];
#pragma unroll
    for (int cb = 0; cb < 4; ++cb) { asv[cb] = a2sw[cb * 16 + col]; adv[cb] = a2dw[cb * 16 + col]; }

    int ntile = (N + 15) >> 4;
    for (int t = wid; t < ntile; t += nwav) {
        int n0 = t * 16;
        int node = n0 + col; if (node >= N) node = N - 1;
        const unsigned short* xr = out1b + (size_t)node * 128;
        f32x4 acc0 = {0.f, 0.f, 0.f, 0.f}, acc1 = acc0, acc2 = acc0, acc3 = acc0;
#pragma unroll
        for (int ks = 0; ks < 4; ++ks) {
            short8v a = *reinterpret_cast<const short8v*>(xr + ks * 32 + g4 * 8);
            acc0 = __builtin_amdgcn_mfma_f32_16x16x32_bf16(a, Bf[ks][0], acc0, 0, 0, 0);
            acc1 = __builtin_amdgcn_mfma_f32_16x16x32_bf16(a, Bf[ks][1], acc1, 0, 0, 0);
            acc2 = __builtin_amdgcn_mfma_f32_16x16x32_bf16(a, Bf[ks][2], acc2, 0, 0, 0);
            acc3 = __builtin_amdgcn_mfma_f32_16x16x32_bf16(a, Bf[ks][3], acc3, 0, 0, 0);
        }
        float ps[4] = {0.f, 0.f, 0.f, 0.f}, pd[4] = {0.f, 0.f, 0.f, 0.f};
#define G2A_EPI(CB, ACC)                                                      \
        {                                                                     \
            _Pragma("unroll")                                                 \
            for (int i = 0; i < 4; ++i) {                                     \
                float v = ACC[i];                                             \
                int r = n0 + g4 * 4 + i;                                      \
                if (r < N) h2b[(size_t)r * 64 + CB * 16 + col] = f2bf_rne(v); \
                ps[i] = fmaf(v, asv[CB], ps[i]);                              \
                pd[i] = fmaf(v, adv[CB], pd[i]);                              \
            }                                                                 \
        }
        G2A_EPI(0, acc0) G2A_EPI(1, acc1) G2A_EPI(2, acc2) G2A_EPI(3, acc3)
#undef G2A_EPI
#pragma unroll
        for (int i = 0; i < 4; ++i) {
            ps[i] += __shfl_xor(ps[i], 1); ps[i] += __shfl_xor(ps[i], 2);
            ps[i] += __shfl_xor(ps[i], 4); ps[i] += __shfl_xor(ps[i], 8);
            pd[i] += __shfl_xor(pd[i], 1); pd[i] += __shfl_xor(pd[i], 2);
            pd[i] += __shfl_xor(pd[i], 4); pd[i] += __shfl_xor(pd[i], 8);
        }
        if (col == 0) {
#pragma unroll
            for (int i = 0; i < 4; ++i) {
                int r = n0 + g4 * 4 + i;
                if (r < N) { a2s[r] = ps[i]; a2d[r] = pd[i]; }
            }
        }
    }
}

// ---------------------------------------------------------------------------
// GATConv2 aggregation + bias. Half-wave per edge, packed bf16. Output bf16.
// ---------------------------------------------------------------------------
__global__ __launch_bounds__(256) void k_g2b(const int* __restrict__ rowptr,
                                             const int* __restrict__ col,
                                             const unsigned int* __restrict__ h2u,
                                             const float* __restrict__ a2s,
                                             const float* __restrict__ a2d,
                                             const float* __restrict__ gb2,
                                             unsigned int* __restrict__ gu, int N) {
    int tid = threadIdx.x, lane = tid & 63;
    int n0 = blockIdx.x * 4 + (tid >> 6);
    int n  = __builtin_amdgcn_readfirstlane(n0 < N ? n0 : N - 1);

    int start = rowptr[n], end = rowptr[n + 1];
    int h = lane >> 5, c = lane & 31;
    float ad = a2d[n];

    float den = 0.f, accL = 0.f, accH = 0.f;
    if (h == 0) {
        float w = __expf(lrelu(a2s[n] + ad));
        unsigned int u = h2u[(size_t)n * 32 + c];
        den = w; accL = w * bf_lo(u); accH = w * bf_hi(u);
    }
    for (int e = start + h; e < end; e += 2) {
        int s = col[e];
        float w = __expf(lrelu(a2s[s] + ad));
        unsigned int u = h2u[(size_t)s * 32 + c];
        den += w;
        accL = fmaf(w, bf_lo(u), accL);
        accH = fmaf(w, bf_hi(u), accH);
    }
    den  += __shfl_xor(den, 32);
    accL += __shfl_xor(accL, 32);
    accH += __shfl_xor(accH, 32);

    if (n0 < N && h == 0) {
        float inv = 1.f / den;
        gu[(size_t)n * 32 + c] = pack_bf16(accL * inv + gb2[2 * c],
                                           accH * inv + gb2[2 * c + 1]);
    }
}

// ---------------------------------------------------------------------------
// Classifier via MFMA: sigmoid(relu([m,g] @ Wf + bc) @ cW2 + cb2)
// Wave = 16-node tile; Wf bf16 register-resident.
// ---------------------------------------------------------------------------
__global__ __launch_bounds__(256) void k_cls(const unsigned short* __restrict__ mb,
                                             const unsigned short* __restrict__ gb,
                                             const unsigned short* __restrict__ Wf,
                                             const float* __restrict__ bc,
                                             const float* __restrict__ cW2,
                                             const float* __restrict__ cb2,
                                             float* __restrict__ out, int N) {
    int lane = threadIdx.x & 63;
    int wid  = (blockIdx.x * blockDim.x + threadIdx.x) >> 6;
    int nwav = (gridDim.x * blockDim.x) >> 6;
    int col = lane & 15, g4 = lane >> 4;

    short8v Bf[4][4];
#pragma unroll
    for (int ks = 0; ks < 4; ++ks)
#pragma unroll
        for (int cb = 0; cb < 4; ++cb) {
            union { short8v v; unsigned short u[8]; } bu;
#pragma unroll
            for (int j = 0; j < 8; ++j)
                bu.u[j] = Wf[(ks * 32 + g4 * 8 + j) * 64 + cb * 16 + col];
            Bf[ks][cb] = bu.v;
        }
    float w2v[4], bcv[4];
#pragma unroll
    for (int cb = 0; cb < 4; ++cb) { w2v[cb] = cW2[cb * 16 + col]; bcv[cb] = bc[cb * 16 + col]; }
    float cb2v = cb2[0];

    int ntile = (N + 15) >> 4;
    for (int t = wid; t < ntile; t += nwav) {
        int n0 = t * 16;
        int node = n0 + col; if (node >= N) node = N - 1;
        const unsigned short* mr = mb + (size_t)node * 64;
        const unsigned short* gr = gb + (size_t)node * 64;
        f32x4 acc0 = {0.f, 0.f, 0.f, 0.f}, acc1 = acc0, acc2 = acc0, acc3 = acc0;
#pragma unroll
        for (int ks = 0; ks < 4; ++ks) {
            short8v a = (ks < 2)
                ? *reinterpret_cast<const short8v*>(mr + ks * 32 + g4 * 8)
                : *reinterpret_cast<const short8v*>(gr + (ks - 2) * 32 + g4 * 8);
            acc0 = __builtin_amdgcn_mfma_f32_16x16x32_bf16(a, Bf[ks][0], acc0, 0, 0, 0);
            acc1 = __builtin_amdgcn_mfma_f32_16x16x32_bf16(a, Bf[ks][1], acc1, 0, 0, 0);
            acc2 = __builtin_amdgcn_mfma_f32_16x16x32_bf16(a, Bf[ks][2], acc2, 0, 0, 0);
            acc3 = __builtin_amdgcn_mfma_f32_16x16x32_bf16(a, Bf[ks][3], acc3, 0, 0, 0);
        }
        float z[4] = {0.f, 0.f, 0.f, 0.f};
#define CLS_EPI(CB, ACC)                                                   \
        {                                                                  \
            _Pragma("unroll")                                              \
            for (int i = 0; i < 4; ++i)                                    \
                z[i] = fmaf(fmaxf(ACC[i] + bcv[CB], 0.f), w2v[CB], z[i]);  \
        }
        CLS_EPI(0, acc0) CLS_EPI(1, acc1) CLS_EPI(2, acc2) CLS_EPI(3, acc3)
#undef CLS_EPI
#pragma unroll
        for (int i = 0; i < 4; ++i) {
            z[i] += __shfl_xor(z[i], 1); z[i] += __shfl_xor(z[i], 2);
            z[i] += __shfl_xor(z[i], 4); z[i] += __shfl_xor(z[i], 8);
        }
        if (col == 0) {
#pragma unroll
            for (int i = 0; i < 4; ++i) {
                int r = n0 + g4 * 4 + i;
                if (r < N) out[r] = 1.f / (1.f + __expf(-(z[i] + cb2v)));
            }
        }
    }
}

// ---------------------------------------------------------------------------
extern "C" void kernel_launch(void* const* d_in, const int* in_sizes, int n_in,
                              void* d_out, int out_size, void* d_ws, size_t ws_size,
                              hipStream_t stream) {
    const float* td   = (const float*)d_in[0];
    const float* x    = (const float*)d_in[1];
    const int*   ei   = (const int*)d_in[2];
    const float* tW1  = (const float*)d_in[3];
    const float* tb1  = (const float*)d_in[4];
    const float* tW2  = (const float*)d_in[5];
    const float* tb2  = (const float*)d_in[6];
    const float* gW1  = (const float*)d_in[7];
    const float* ga1s = (const float*)d_in[8];
    const float* ga1d = (const float*)d_in[9];
    const float* gb1  = (const float*)d_in[10];
    const float* gW2  = (const float*)d_in[11];
    const float* ga2s = (const float*)d_in[12];
    const float* ga2d = (const float*)d_in[13];
    const float* gb2  = (const float*)d_in[14];
    const float* cW1  = (const float*)d_in[15];
    const float* cb1  = (const float*)d_in[16];
    const float* cW2  = (const float*)d_in[17];
    const float* cb2  = (const float*)d_in[18];

    int N = in_sizes[1] / 10;
    int E = in_sizes[2] / 2;

    float* fws = (float*)d_ws;
    unsigned short* mb16   = (unsigned short*)fws;                    // [N,64] bf16
    unsigned short* h1b    = (unsigned short*)(fws + (size_t)N * 32); // [N,128] bf16
    unsigned short* out1b  = (unsigned short*)(fws + (size_t)N * 96); // [N,128] bf16
    float* a1s   = fws + (size_t)N * 160;
    float* a1d   = fws + (size_t)N * 164;
    unsigned short* h2b = h1b;       // reuse (h1 dead after k_g1b)  [N,64] bf16
    float* a2s   = a1s;              // reuse
    float* a2d   = a1d;              // reuse
    unsigned short* gb16 = out1b;    // reuse (out1 dead after k_g2a) [N,64] bf16

    int* ib       = (int*)(fws + (size_t)N * 168);
    int* counts   = ib;
    int* rowptr   = ib + N;
    int* nxt      = ib + 2 * N + 1;
    int* partials = ib + 3 * N + 1;
    int* col      = ib + 3 * N + 1 + 128;

    unsigned short* Wf = (unsigned short*)nxt;  // overlay (dead after k_scatter)
    float* bcf = (float*)(Wf + 8192);

    hipMemsetAsync(counts, 0, (size_t)N * sizeof(int), stream);

    int NB = (N + 1023) / 1024;
    int range = (N + SC_P - 1) / SC_P;
    k_count  <<<(E + 255) / 256, 256, 0, stream>>>(ei, counts, E);
    k_scan1  <<<NB, 1024, 0, stream>>>(counts, rowptr, partials, N);
    k_scan3  <<<(N + 1 + 255) / 256, 256, 0, stream>>>(rowptr, partials, nxt, N);
    k_scatter<<<(E + 256 * SC_K - 1) / (256 * SC_K), 256, 0, stream>>>(ei, nxt, col, E, range);
    k_fuse   <<<33, 256, 0, stream>>>(tW2, cW1, tb2, cb1, Wf, bcf);

    int nb4   = (N + 3) / 4;
    int ntile = (N + 15) / 16;
    int nbt   = (ntile + 3) / 4;
    k_temporal<<<2048, 256, 0, stream>>>(td, tW1, tb1, mb16, N);
    k_g1a     <<<nb4, 256, 0, stream>>>(x, gW1, ga1s, ga1d, h1b, a1s, a1d, N);
    k_g1b     <<<nb4, 256, 0, stream>>>(rowptr, col, (const unsigned int*)h1b, a1s, a1d, gb1,
                                        (unsigned int*)out1b, N);
    k_g2a     <<<nbt, 256, 0, stream>>>(out1b, gW2, ga2s, ga2d, h2b, a2s, a2d, N);
    k_g2b     <<<nb4, 256, 0, stream>>>(rowptr, col, (const unsigned int*)h2b, a2s, a2d, gb2,
                                        (unsigned int*)gb16, N);
    k_cls     <<<nbt, 256, 0, stream>>>(mb16, gb16, Wf, bcf, cW2, cb2, (float*)d_out, N);
}

// Round 7
// 468.031 us; speedup vs baseline: 1.9711x; 1.0303x over previous
//
#include <hip/hip_runtime.h>
#include <hip/hip_bf16.h>

#define DEV_INLINE __device__ __forceinline__

typedef __attribute__((ext_vector_type(8))) short short8v;
typedef __attribute__((ext_vector_type(4))) float f32x4;

DEV_INLINE float lrelu(float v) { return fmaxf(v, 0.2f * v); }

DEV_INLINE unsigned int cvt_pk_bf16(float lo, float hi) {
    unsigned int r;
    asm("v_cvt_pk_bf16_f32 %0, %1, %2" : "=v"(r) : "v"(lo), "v"(hi));
    return r;
}

DEV_INLINE unsigned short f2bf_rne(float f) {
    unsigned int b = __float_as_uint(f);
    return (unsigned short)((b + 0x7FFFu + ((b >> 16) & 1u)) >> 16);
}

DEV_INLINE unsigned int pack_bf16(float lo, float hi) {
    return (unsigned int)f2bf_rne(lo) | ((unsigned int)f2bf_rne(hi) << 16);
}

DEV_INLINE float bf_lo(unsigned int u) { return __uint_as_float(u << 16); }
DEV_INLINE float bf_hi(unsigned int u) { return __uint_as_float(u & 0xFFFF0000u); }

// ---------------------------------------------------------------------------
// CSR scan kernels
// ---------------------------------------------------------------------------
__global__ __launch_bounds__(1024) void k_scan1(const int* __restrict__ counts,
                                                int* __restrict__ rowptr,
                                                int* __restrict__ partials, int N) {
    __shared__ int sd[1024];
    int li = threadIdx.x;
    int i  = blockIdx.x * 1024 + li;
    int v  = (i < N) ? counts[i] : 0;
    sd[li] = v;
    __syncthreads();
    for (int off = 1; off < 1024; off <<= 1) {
        int t = (li >= off) ? sd[li - off] : 0;
        __syncthreads();
        sd[li] += t;
        __syncthreads();
    }
    int inc = sd[li];
    if (i < N) rowptr[i + 1] = inc;
    if (li == 1023) partials[blockIdx.x] = inc;   // raw chunk totals
}

__global__ void k_scan3(int* __restrict__ rowptr, const int* __restrict__ partials,
                        int* __restrict__ nxt, int N) {
    int i = blockIdx.x * blockDim.x + threadIdx.x;
    if (i > N) return;
    int v;
    if (i == 0) { v = 0; rowptr[0] = 0; }
    else {
        int blk = (i - 1) >> 10;
        int pp = 0;
        for (int b = 0; b < blk; ++b) pp += partials[b];
        v = rowptr[i] + pp;
        rowptr[i] = v;
    }
    if (i < N) nxt[i] = v;
}

#define SC_K 8
#define SC_P 16
__global__ __launch_bounds__(256) void k_scatter(const int* __restrict__ ei,
                                                 int* __restrict__ nxt,
                                                 int* __restrict__ col,
                                                 int E, int range) {
    int t = threadIdx.x;
    int base = blockIdx.x * (256 * SC_K);
    int s[SC_K], d[SC_K];
#pragma unroll
    for (int k = 0; k < SC_K; ++k) {
        int e = base + k * 256 + t;
        bool v = (e < E);
        s[k] = v ? ei[e] : 0;
        d[k] = v ? ei[E + e] : -1;
    }
    int lo = 0;
    for (int p = 0; p < SC_P; ++p, lo += range) {
        int hi = lo + range;
#pragma unroll
        for (int k = 0; k < SC_K; ++k) {
            if (d[k] >= lo && d[k] < hi) {
                int pos = atomicAdd(&nxt[d[k]], 1);
                col[pos] = s[k];
            }
        }
        __syncthreads();
    }
}

// ---------------------------------------------------------------------------
// Fused front kernel: edge-count histogram + classifier-weight fuse +
// temporal encoder (LDS-staged coalesced loads, MFMA) + GATConv1 projection.
// One wave per node per iteration; grid-stride.
// ---------------------------------------------------------------------------
__global__ __launch_bounds__(256) void k_tg1(const float* __restrict__ td,
                                             const float* __restrict__ tW1,
                                             const float* __restrict__ tb1,
                                             const float* __restrict__ x,
                                             const float* __restrict__ gW1,
                                             const float* __restrict__ as_w,
                                             const float* __restrict__ ad_w,
                                             const float* __restrict__ tW2,
                                             const float* __restrict__ cW1,
                                             const float* __restrict__ tb2,
                                             const float* __restrict__ cb1,
                                             const int* __restrict__ ei,
                                             int* __restrict__ counts,
                                             unsigned short* __restrict__ mb,
                                             unsigned short* __restrict__ h1b,
                                             float* __restrict__ a1s,
                                             float* __restrict__ a1d,
                                             unsigned short* __restrict__ Wf,
                                             float* __restrict__ bcf,
                                             int N, int E) {
    __shared__ float lds[4][512];
    int tid = threadIdx.x, lane = tid & 63, wv = tid >> 6;
    int gid = blockIdx.x * 256 + tid;

    // ---- folded k_count (grid-stride over edges) ----
    int estr = gridDim.x * 256;
    for (int e = gid; e < E; e += estr) atomicAdd(&counts[ei[E + e]], 1);

    // ---- folded k_fuse ----
    if (gid < 4096) {
        int i = gid >> 6, c = gid & 63;
        float s = 0.f;
#pragma unroll 8
        for (int k = 0; k < 64; ++k) s = fmaf(tW2[i * 64 + k], cW1[k * 64 + c], s);
        Wf[gid] = f2bf_rne(s);
    } else if (gid < 8192) {
        Wf[gid] = f2bf_rne(cW1[gid]);
    } else if (gid < 8256) {
        int c = gid - 8192;
        float s = cb1[c];
#pragma unroll 8
        for (int k = 0; k < 64; ++k) s = fmaf(tb2[k], cW1[k * 64 + c], s);
        bcf[c] = s;
    }

    // ---- per-wave constants ----
    int col = lane & 15, g = lane >> 4;

    // temporal B-frags (bias folded at k=10)
    short8v B[4];
#pragma unroll
    for (int cb = 0; cb < 4; ++cb) {
        union { short8v v; unsigned short u[8]; } bu;
#pragma unroll
        for (int j = 0; j < 8; ++j) {
            int f = g * 8 + j;
            int c = cb * 16 + col;
            float w = (f < 10) ? tW1[f * 64 + c] : ((f == 10) ? tb1[c] : 0.f);
            bu.u[j] = f2bf_rne(w);
        }
        B[cb] = bu.v;
    }
    // g1a weights: lane = channel (0..63) of each 64-ch half
    float wa[10], wb[10];
#pragma unroll
    for (int i = 0; i < 10; ++i) { wa[i] = gW1[i * 128 + lane]; wb[i] = gW1[i * 128 + 64 + lane]; }
    int c31 = lane & 31;
    int headA = lane >> 5;
    float asA = as_w[headA * 32 + c31], asB = as_w[(headA + 2) * 32 + c31];
    float adA = ad_w[headA * 32 + c31], adB = ad_w[(headA + 2) * 32 + c31];

    float* wbase = lds[wv];
    int wid  = blockIdx.x * 4 + wv;
    int nwav = gridDim.x * 4;

    for (int n = wid; n < N; n += nwav) {
        // ---- stage td row (500 floats) coalesced into LDS ----
        const float4* r4 = reinterpret_cast<const float4*>(td + (size_t)n * 500);
        float4 v0 = r4[lane];
        *reinterpret_cast<float4*>(wbase + 4 * lane) = v0;
        if (lane < 61) {
            float4 v1 = r4[64 + lane];
            *reinterpret_cast<float4*>(wbase + 256 + 4 * lane) = v1;
        }
        asm volatile("s_waitcnt lgkmcnt(0)" ::: "memory");

        // ---- temporal MFMA over 4 row-tiles ----
        float sum0 = 0.f, sum1 = 0.f, sum2 = 0.f, sum3 = 0.f;
#pragma unroll
        for (int tt = 0; tt < 4; ++tt) {
            int t = tt * 16 + col;
            bool valid = (t < 50);
            float x0 = 0.f, x1 = 0.f, x2 = 0.f, x3 = 0.f;
            float x4 = 0.f, x5 = 0.f, x6 = 0.f, x7 = 0.f;
            const float* rp = wbase + t * 10;
            if (g == 0 && valid) {
                float2 p0 = *reinterpret_cast<const float2*>(rp);
                float2 p1 = *reinterpret_cast<const float2*>(rp + 2);
                float2 p2 = *reinterpret_cast<const float2*>(rp + 4);
                float2 p3 = *reinterpret_cast<const float2*>(rp + 6);
                x0 = p0.x; x1 = p0.y; x2 = p1.x; x3 = p1.y;
                x4 = p2.x; x5 = p2.y; x6 = p3.x; x7 = p3.y;
            } else if (g == 1 && valid) {
                float2 p4 = *reinterpret_cast<const float2*>(rp + 8);
                x0 = p4.x; x1 = p4.y; x2 = 1.0f;
            }
            union { short8v v; unsigned int w[4]; } au;
            au.w[0] = cvt_pk_bf16(x0, x1);
            au.w[1] = cvt_pk_bf16(x2, x3);
            au.w[2] = cvt_pk_bf16(x4, x5);
            au.w[3] = cvt_pk_bf16(x6, x7);

            f32x4 z = {0.f, 0.f, 0.f, 0.f};
            f32x4 c0 = __builtin_amdgcn_mfma_f32_16x16x32_bf16(au.v, B[0], z, 0, 0, 0);
            f32x4 c1 = __builtin_amdgcn_mfma_f32_16x16x32_bf16(au.v, B[1], z, 0, 0, 0);
            f32x4 c2 = __builtin_amdgcn_mfma_f32_16x16x32_bf16(au.v, B[2], z, 0, 0, 0);
            f32x4 c3 = __builtin_amdgcn_mfma_f32_16x16x32_bf16(au.v, B[3], z, 0, 0, 0);
#pragma unroll
            for (int i = 0; i < 4; ++i) {
                sum0 += fmaxf(c0[i], 0.f);
                sum1 += fmaxf(c1[i], 0.f);
                sum2 += fmaxf(c2[i], 0.f);
                sum3 += fmaxf(c3[i], 0.f);
            }
        }
        sum0 += __shfl_xor(sum0, 16); sum0 += __shfl_xor(sum0, 32);
        sum1 += __shfl_xor(sum1, 16); sum1 += __shfl_xor(sum1, 32);
        sum2 += __shfl_xor(sum2, 16); sum2 += __shfl_xor(sum2, 32);
        sum3 += __shfl_xor(sum3, 16); sum3 += __shfl_xor(sum3, 32);
        float mv = (g == 0) ? sum0 : (g == 1) ? sum1 : (g == 2) ? sum2 : sum3;
        mb[(size_t)n * 64 + lane] = f2bf_rne(mv * 0.02f);

        // ---- GATConv1 projection + attention scores for node n ----
        const float* xp = x + (size_t)n * 10;
        float ha = 0.f, hb = 0.f;
#pragma unroll
        for (int i = 0; i < 10; ++i) { float xv = xp[i]; ha = fmaf(xv, wa[i], ha); hb = fmaf(xv, wb[i], hb); }
        float ps_a = ha * asA, ps_b = hb * asB;
        float pd_a = ha * adA, pd_b = hb * adB;
#pragma unroll
        for (int m = 1; m < 32; m <<= 1) {
            ps_a += __shfl_xor(ps_a, m); ps_b += __shfl_xor(ps_b, m);
            pd_a += __shfl_xor(pd_a, m); pd_b += __shfl_xor(pd_b, m);
        }
        h1b[(size_t)n * 128 + lane]      = f2bf_rne(ha);
        h1b[(size_t)n * 128 + 64 + lane] = f2bf_rne(hb);
        if (c31 == 0) {
            a1s[n * 4 + headA]     = ps_a;
            a1s[n * 4 + 2 + headA] = ps_b;
            a1d[n * 4 + headA]     = pd_a;
            a1d[n * 4 + 2 + headA] = pd_b;
        }
    }
}

// ---------------------------------------------------------------------------
// GATConv1 aggregation + bias + ELU. Lane l owns channels (2l,2l+1), head l>>4.
// ---------------------------------------------------------------------------
__global__ __launch_bounds__(256) void k_g1b(const int* __restrict__ rowptr,
                                             const int* __restrict__ col,
                                             const unsigned int* __restrict__ h1u,
                                             const float* __restrict__ a1s,
                                             const float* __restrict__ a1d,
                                             const float* __restrict__ gb1,
                                             unsigned int* __restrict__ out1u, int N) {
    int tid = threadIdx.x, lane = tid & 63;
    int n0 = blockIdx.x * 4 + (tid >> 6);
    int n  = __builtin_amdgcn_readfirstlane(n0 < N ? n0 : N - 1);

    int start = rowptr[n], end = rowptr[n + 1];
    int hsel = lane >> 4;
    float advh = a1d[n * 4 + hsel];
    float gbl  = gb1[2 * lane];
    float gbh  = gb1[2 * lane + 1];

    float w  = __expf(lrelu(a1s[n * 4 + hsel] + advh));
    float den = w;
    unsigned int u = h1u[(size_t)n * 64 + lane];
    float accL = w * bf_lo(u), accH = w * bf_hi(u);

    int e = start;
    for (; e + 2 <= end; e += 2) {
        int s0 = col[e], s1 = col[e + 1];
        float q0 = a1s[s0 * 4 + hsel];
        float q1 = a1s[s1 * 4 + hsel];
        unsigned int u0 = h1u[(size_t)s0 * 64 + lane];
        unsigned int u1 = h1u[(size_t)s1 * 64 + lane];
        float w0 = __expf(lrelu(q0 + advh));
        float w1 = __expf(lrelu(q1 + advh));
        den += w0 + w1;
        accL = fmaf(w0, bf_lo(u0), accL);
        accH = fmaf(w0, bf_hi(u0), accH);
        accL = fmaf(w1, bf_lo(u1), accL);
        accH = fmaf(w1, bf_hi(u1), accH);
    }
    if (e < end) {
        int s = col[e];
        float q = a1s[s * 4 + hsel];
        unsigned int us = h1u[(size_t)s * 64 + lane];
        float ws = __expf(lrelu(q + advh));
        den += ws;
        accL = fmaf(ws, bf_lo(us), accL);
        accH = fmaf(ws, bf_hi(us), accH);
    }

    float inv = 1.f / den;
    float vL = accL * inv + gbl;
    float vH = accH * inv + gbh;
    vL = (vL > 0.f) ? vL : (__expf(vL) - 1.f);   // ELU
    vH = (vH > 0.f) ? vH : (__expf(vH) - 1.f);
    if (n0 < N) out1u[(size_t)n * 64 + lane] = pack_bf16(vL, vH);
}

// ---------------------------------------------------------------------------
// GATConv2 projection via MFMA: h2 = out1 @ gW2 (bf16 in/out) + scores.
// ---------------------------------------------------------------------------
__global__ __launch_bounds__(256) void k_g2a(const unsigned short* __restrict__ out1b,
                                             const float* __restrict__ gW2,
                                             const float* __restrict__ a2sw,
                                             const float* __restrict__ a2dw,
                                             unsigned short* __restrict__ h2b,
                                             float* __restrict__ a2s,
                                             float* __restrict__ a2d, int N) {
    int lane = threadIdx.x & 63;
    int wid  = (blockIdx.x * blockDim.x + threadIdx.x) >> 6;
    int nwav = (gridDim.x * blockDim.x) >> 6;
    int col = lane & 15, g4 = lane >> 4;

    short8v Bf[4][4];
#pragma unroll
    for (int ks = 0; ks < 4; ++ks)
#pragma unroll
        for (int cb = 0; cb < 4; ++cb) {
            union { short8v v; unsigned short u[8]; } bu;
#pragma unroll
            for (int j = 0; j < 8; ++j)
                bu.u[j] = f2bf_rne(gW2[(ks * 32 + g4 * 8 + j) * 64 + cb * 16 + col]);
            Bf[ks][cb] = bu.v;
        }
    float asv[4], adv[4];
#pragma unroll
    for (int cb = 0; cb < 4; ++cb) { asv[cb] = a2sw[cb * 16 + col]; adv[cb] = a2dw[cb * 16 + col]; }

    int ntile = (N + 15) >> 4;
    for (int t = wid; t < ntile; t += nwav) {
        int n0 = t * 16;
        int node = n0 + col; if (node >= N) node = N - 1;
        const unsigned short* xr = out1b + (size_t)node * 128;
        f32x4 acc0 = {0.f, 0.f, 0.f, 0.f}, acc1 = acc0, acc2 = acc0, acc3 = acc0;
#pragma unroll
        for (int ks = 0; ks < 4; ++ks) {
            short8v a = *reinterpret_cast<const short8v*>(xr + ks * 32 + g4 * 8);
            acc0 = __builtin_amdgcn_mfma_f32_16x16x32_bf16(a, Bf[ks][0], acc0, 0, 0, 0);
            acc1 = __builtin_amdgcn_mfma_f32_16x16x32_bf16(a, Bf[ks][1], acc1, 0, 0, 0);
            acc2 = __builtin_amdgcn_mfma_f32_16x16x32_bf16(a, Bf[ks][2], acc2, 0, 0, 0);
            acc3 = __builtin_amdgcn_mfma_f32_16x16x32_bf16(a, Bf[ks][3], acc3, 0, 0, 0);
        }
        float ps[4] = {0.f, 0.f, 0.f, 0.f}, pd[4] = {0.f, 0.f, 0.f, 0.f};
#define G2A_EPI(CB, ACC)                                                      \
        {                                                                     \
            _Pragma("unroll")                                                 \
            for (int i = 0; i < 4; ++i) {                                     \
                float v = ACC[i];                                             \
                int r = n0 + g4 * 4 + i;                                      \
                if (r < N) h2b[(size_t)r * 64 + CB * 16 + col] = f2bf_rne(v); \
                ps[i] = fmaf(v, asv[CB], ps[i]);                              \
                pd[i] = fmaf(v, adv[CB], pd[i]);                              \
            }                                                                 \
        }
        G2A_EPI(0, acc0) G2A_EPI(1, acc1) G2A_EPI(2, acc2) G2A_EPI(3, acc3)
#undef G2A_EPI
#pragma unroll
        for (int i = 0; i < 4; ++i) {
            ps[i] += __shfl_xor(ps[i], 1); ps[i] += __shfl_xor(ps[i], 2);
            ps[i] += __shfl_xor(ps[i], 4); ps[i] += __shfl_xor(ps[i], 8);
            pd[i] += __shfl_xor(pd[i], 1); pd[i] += __shfl_xor(pd[i], 2);
            pd[i] += __shfl_xor(pd[i], 4); pd[i] += __shfl_xor(pd[i], 8);
        }
        if (col == 0) {
#pragma unroll
            for (int i = 0; i < 4; ++i) {
                int r = n0 + g4 * 4 + i;
                if (r < N) { a2s[r] = ps[i]; a2d[r] = pd[i]; }
            }
        }
    }
}

// ---------------------------------------------------------------------------
// GATConv2 aggregation + bias. Half-wave per edge, packed bf16. Output bf16.
// ---------------------------------------------------------------------------
__global__ __launch_bounds__(256) void k_g2b(const int* __restrict__ rowptr,
                                             const int* __restrict__ col,
                                             const unsigned int* __restrict__ h2u,
                                             const float* __restrict__ a2s,
                                             const float* __restrict__ a2d,
                                             const float* __restrict__ gb2,
                                             unsigned int* __restrict__ gu, int N) {
    int tid = threadIdx.x, lane = tid & 63;
    int n0 = blockIdx.x * 4 + (tid >> 6);
    int n  = __builtin_amdgcn_readfirstlane(n0 < N ? n0 : N - 1);

    int start = rowptr[n], end = rowptr[n + 1];
    int h = lane >> 5, c = lane & 31;
    float ad = a2d[n];

    float den = 0.f, accL = 0.f, accH = 0.f;
    if (h == 0) {
        float w = __expf(lrelu(a2s[n] + ad));
        unsigned int u = h2u[(size_t)n * 32 + c];
        den = w; accL = w * bf_lo(u); accH = w * bf_hi(u);
    }
    for (int e = start + h; e < end; e += 2) {
        int s = col[e];
        float w = __expf(lrelu(a2s[s] + ad));
        unsigned int u = h2u[(size_t)s * 32 + c];
        den += w;
        accL = fmaf(w, bf_lo(u), accL);
        accH = fmaf(w, bf_hi(u), accH);
    }
    den  += __shfl_xor(den, 32);
    accL += __shfl_xor(accL, 32);
    accH += __shfl_xor(accH, 32);

    if (n0 < N && h == 0) {
        float inv = 1.f / den;
        gu[(size_t)n * 32 + c] = pack_bf16(accL * inv + gb2[2 * c],
                                           accH * inv + gb2[2 * c + 1]);
    }
}

// ---------------------------------------------------------------------------
// Classifier via MFMA: sigmoid(relu([m,g] @ Wf + bc) @ cW2 + cb2)
// ---------------------------------------------------------------------------
__global__ __launch_bounds__(256) void k_cls(const unsigned short* __restrict__ mb,
                                             const unsigned short* __restrict__ gb,
                                             const unsigned short* __restrict__ Wf,
                                             const float* __restrict__ bc,
                                             const float* __restrict__ cW2,
                                             const float* __restrict__ cb2,
                                             float* __restrict__ out, int N) {
    int lane = threadIdx.x & 63;
    int wid  = (blockIdx.x * blockDim.x + threadIdx.x) >> 6;
    int nwav = (gridDim.x * blockDim.x) >> 6;
    int col = lane & 15, g4 = lane >> 4;

    short8v Bf[4][4];
#pragma unroll
    for (int ks = 0; ks < 4; ++ks)
#pragma unroll
        for (int cb = 0; cb < 4; ++cb) {
            union { short8v v; unsigned short u[8]; } bu;
#pragma unroll
            for (int j = 0; j < 8; ++j)
                bu.u[j] = Wf[(ks * 32 + g4 * 8 + j) * 64 + cb * 16 + col];
            Bf[ks][cb] = bu.v;
        }
    float w2v[4], bcv[4];
#pragma unroll
    for (int cb = 0; cb < 4; ++cb) { w2v[cb] = cW2[cb * 16 + col]; bcv[cb] = bc[cb * 16 + col]; }
    float cb2v = cb2[0];

    int ntile = (N + 15) >> 4;
    for (int t = wid; t < ntile; t += nwav) {
        int n0 = t * 16;
        int node = n0 + col; if (node >= N) node = N - 1;
        const unsigned short* mr = mb + (size_t)node * 64;
        const unsigned short* gr = gb + (size_t)node * 64;
        f32x4 acc0 = {0.f, 0.f, 0.f, 0.f}, acc1 = acc0, acc2 = acc0, acc3 = acc0;
#pragma unroll
        for (int ks = 0; ks < 4; ++ks) {
            short8v a = (ks < 2)
                ? *reinterpret_cast<const short8v*>(mr + ks * 32 + g4 * 8)
                : *reinterpret_cast<const short8v*>(gr + (ks - 2) * 32 + g4 * 8);
            acc0 = __builtin_amdgcn_mfma_f32_16x16x32_bf16(a, Bf[ks][0], acc0, 0, 0, 0);
            acc1 = __builtin_amdgcn_mfma_f32_16x16x32_bf16(a, Bf[ks][1], acc1, 0, 0, 0);
            acc2 = __builtin_amdgcn_mfma_f32_16x16x32_bf16(a, Bf[ks][2], acc2, 0, 0, 0);
            acc3 = __builtin_amdgcn_mfma_f32_16x16x32_bf16(a, Bf[ks][3], acc3, 0, 0, 0);
        }
        float z[4] = {0.f, 0.f, 0.f, 0.f};
#define CLS_EPI(CB, ACC)                                                   \
        {                                                                  \
            _Pragma("unroll")                                              \
            for (int i = 0; i < 4; ++i)                                    \
                z[i] = fmaf(fmaxf(ACC[i] + bcv[CB], 0.f), w2v[CB], z[i]);  \
        }
        CLS_EPI(0, acc0) CLS_EPI(1, acc1) CLS_EPI(2, acc2) CLS_EPI(3, acc3)
#undef CLS_EPI
#pragma unroll
        for (int i = 0; i < 4; ++i) {
            z[i] += __shfl_xor(z[i], 1); z[i] += __shfl_xor(z[i], 2);
            z[i] += __shfl_xor(z[i], 4); z[i] += __shfl_xor(z[i], 8);
        }
        if (col == 0) {
#pragma unroll
            for (int i = 0; i < 4; ++i) {
                int r = n0 + g4 * 4 + i;
                if (r < N) out[r] = 1.f / (1.f + __expf(-(z[i] + cb2v)));
            }
        }
    }
}

// ---------------------------------------------------------------------------
extern "C" void kernel_launch(void* const* d_in, const int* in_sizes, int n_in,
                              void* d_out, int out_size, void* d_ws, size_t ws_size,
                              hipStream_t stream) {
    const float* td   = (const float*)d_in[0];
    const float* x    = (const float*)d_in[1];
    const int*   ei   = (const int*)d_in[2];
    const float* tW1  = (const float*)d_in[3];
    const float* tb1  = (const float*)d_in[4];
    const float* tW2  = (const float*)d_in[5];
    const float* tb2  = (const float*)d_in[6];
    const float* gW1  = (const float*)d_in[7];
    const float* ga1s = (const float*)d_in[8];
    const float* ga1d = (const float*)d_in[9];
    const float* gb1  = (const float*)d_in[10];
    const float* gW2  = (const float*)d_in[11];
    const float* ga2s = (const float*)d_in[12];
    const float* ga2d = (const float*)d_in[13];
    const float* gb2  = (const float*)d_in[14];
    const float* cW1  = (const float*)d_in[15];
    const float* cb1  = (const float*)d_in[16];
    const float* cW2  = (const float*)d_in[17];
    const float* cb2  = (const float*)d_in[18];

    int N = in_sizes[1] / 10;
    int E = in_sizes[2] / 2;

    float* fws = (float*)d_ws;
    unsigned short* mb16   = (unsigned short*)fws;                    // [N,64] bf16
    unsigned short* h1b    = (unsigned short*)(fws + (size_t)N * 32); // [N,128] bf16
    unsigned short* out1b  = (unsigned short*)(fws + (size_t)N * 96); // [N,128] bf16
    float* a1s   = fws + (size_t)N * 160;
    float* a1d   = fws + (size_t)N * 164;
    unsigned short* h2b = h1b;       // reuse (h1 dead after k_g1b)  [N,64] bf16
    float* a2s   = a1s;              // reuse
    float* a2d   = a1d;              // reuse
    unsigned short* gb16 = out1b;    // reuse (out1 dead after k_g2a) [N,64] bf16

    int* ib       = (int*)(fws + (size_t)N * 168);
    int* counts   = ib;
    int* rowptr   = ib + N;
    int* nxt      = ib + 2 * N + 1;
    int* partials = ib + 3 * N + 1;
    int* col      = ib + 3 * N + 1 + 128;

    // Wf/bcf now live PAST col (dedicated; no overlay with nxt — k_tg1 writes
    // them before scan3/scatter touch nxt)
    unsigned short* Wf = (unsigned short*)(col + E);
    float* bcf = (float*)(Wf + 8192);

    hipMemsetAsync(counts, 0, (size_t)N * sizeof(int), stream);

    int NB = (N + 1023) / 1024;
    int range = (N + SC_P - 1) / SC_P;

    // fused count + fuse + temporal + g1a
    k_tg1<<<2048, 256, 0, stream>>>(td, tW1, tb1, x, gW1, ga1s, ga1d,
                                    tW2, cW1, tb2, cb1, ei, counts,
                                    mb16, h1b, a1s, a1d, Wf, bcf, N, E);
    k_scan1  <<<NB, 1024, 0, stream>>>(counts, rowptr, partials, N);
    k_scan3  <<<(N + 1 + 255) / 256, 256, 0, stream>>>(rowptr, partials, nxt, N);
    k_scatter<<<(E + 256 * SC_K - 1) / (256 * SC_K), 256, 0, stream>>>(ei, nxt, col, E, range);

    int nb4   = (N + 3) / 4;
    int ntile = (N + 15) / 16;
    int nbt   = (ntile + 3) / 4;
    k_g1b<<<nb4, 256, 0, stream>>>(rowptr, col, (const unsigned int*)h1b, a1s, a1d, gb1,
                                   (unsigned int*)out1b, N);
    k_g2a<<<nbt, 256, 0, stream>>>(out1b, gW2, ga2s, ga2d, h2b, a2s, a2d, N);
    k_g2b<<<nb4, 256, 0, stream>>>(rowptr, col, (const unsigned int*)h2b, a2s, a2d, gb2,
                                   (unsigned int*)gb16, N);
    k_cls<<<nbt, 256, 0, stream>>>(mb16, gb16, Wf, bcf, cW2, cb2, (float*)d_out, N);
}